// Round 1
// baseline (8677.469 us; speedup 1.0000x reference)
//
#include <hip/hip_runtime.h>

#define N_NODES 100000
#define N_EDGES 1600000
#define N_GRAPHS 512
#define F_IN 20
#define HID 128
#define OUT_F 64

// ---------------- degree / norm ----------------
__global__ void fill_deg(float* deg) {
    int i = blockIdx.x * 256 + threadIdx.x;
    if (i < N_NODES) deg[i] = 1.0f;   // self-loop
}

__global__ void count_deg(const int* __restrict__ dst, float* deg) {
    int e = blockIdx.x * 256 + threadIdx.x;
    if (e < N_EDGES) atomicAdd(&deg[dst[e]], 1.0f);
}

__global__ void make_dinv(float* deg) {
    int i = blockIdx.x * 256 + threadIdx.x;
    if (i < N_NODES) deg[i] = rsqrtf(deg[i]);   // deg >= 1 always
}

// ---------------- GEMM: C[N x 128] = act(A)[N x K] @ W[K x 128] ----------------
// Block: 256 threads, 16 nodes per block. W staged in K-chunks of <=64 rows.
template <int K, bool RELU>
__global__ __launch_bounds__(256) void gemm(const float* __restrict__ A,
                                            const float* __restrict__ W,
                                            float* __restrict__ C) {
    constexpr int KC = (K > 64) ? 64 : K;
    __shared__ float Alds[16 * K];
    __shared__ float Wlds[KC * HID];
    const int t = threadIdx.x;
    const int node0 = blockIdx.x * 16;

    for (int idx = t; idx < 16 * K; idx += 256) {
        float v = A[node0 * K + idx];           // rows contiguous
        if (RELU) v = fmaxf(v, 0.0f);
        Alds[idx] = v;
    }

    const int h4 = (t & 31) * 4;   // output column group (4 floats)
    const int g  = t >> 5;         // node pair id 0..7
    float4 acc0 = make_float4(0.f, 0.f, 0.f, 0.f);
    float4 acc1 = make_float4(0.f, 0.f, 0.f, 0.f);

    for (int k0 = 0; k0 < K; k0 += KC) {
        __syncthreads();
        for (int idx = t; idx < KC * HID; idx += 256)
            Wlds[idx] = W[k0 * HID + idx];
        __syncthreads();
#pragma unroll
        for (int kk = 0; kk < KC; ++kk) {
            float a0 = Alds[(g * 2) * K + k0 + kk];
            float a1 = Alds[(g * 2 + 1) * K + k0 + kk];
            float4 w = *(const float4*)&Wlds[kk * HID + h4];
            acc0.x = fmaf(a0, w.x, acc0.x);
            acc0.y = fmaf(a0, w.y, acc0.y);
            acc0.z = fmaf(a0, w.z, acc0.z);
            acc0.w = fmaf(a0, w.w, acc0.w);
            acc1.x = fmaf(a1, w.x, acc1.x);
            acc1.y = fmaf(a1, w.y, acc1.y);
            acc1.z = fmaf(a1, w.z, acc1.z);
            acc1.w = fmaf(a1, w.w, acc1.w);
        }
    }
    *(float4*)&C[(node0 + g * 2) * HID + h4]     = acc0;
    *(float4*)&C[(node0 + g * 2 + 1) * HID + h4] = acc1;
}

// ---------------- aggregation init: B = bias + dinv^2 * XW (self-loop term) ----------------
__global__ void init_agg(const float* __restrict__ A, const float* __restrict__ dinv,
                         const float* __restrict__ bias, float* __restrict__ B) {
    int idx = blockIdx.x * 256 + threadIdx.x;   // over N_NODES*32
    int n = idx >> 5;
    int h4 = (idx & 31) * 4;
    float di = dinv[n];
    float s = di * di;
    float4 a = *(const float4*)&A[n * HID + h4];
    float4 b4 = *(const float4*)&bias[h4];
    float4 r;
    r.x = fmaf(s, a.x, b4.x);
    r.y = fmaf(s, a.y, b4.y);
    r.z = fmaf(s, a.z, b4.z);
    r.w = fmaf(s, a.w, b4.w);
    *(float4*)&B[n * HID + h4] = r;
}

// ---------------- edge scatter: B[dst] += norm * A[src] ----------------
__global__ __launch_bounds__(256) void scatter(const float* __restrict__ A,
                                               const int* __restrict__ src,
                                               const int* __restrict__ dst,
                                               const float* __restrict__ dinv,
                                               float* B) {
    int t = threadIdx.x;
    int e = blockIdx.x * 8 + (t >> 5);   // grid sized exactly
    int h4 = (t & 31) * 4;
    int s = src[e];
    int d = dst[e];
    float w = dinv[s] * dinv[d];
    float4 a = *(const float4*)&A[s * HID + h4];
    float* bp = &B[d * HID + h4];
    atomicAdd(bp + 0, w * a.x);
    atomicAdd(bp + 1, w * a.y);
    atomicAdd(bp + 2, w * a.z);
    atomicAdd(bp + 3, w * a.w);
}

// ---------------- pooling ----------------
__global__ void zero_pool(float* sums, float* counts) {
    int i = blockIdx.x * 256 + threadIdx.x;
    if (i < N_GRAPHS * HID) sums[i] = 0.f;
    if (i < N_GRAPHS) counts[i] = 0.f;
}

__global__ void pool(const float* __restrict__ B, const int* __restrict__ batch,
                     float* sums) {
    int idx = blockIdx.x * 256 + threadIdx.x;   // over N_NODES*32
    int n = idx >> 5;
    int h4 = (idx & 31) * 4;
    int g = batch[n];
    float4 v = *(const float4*)&B[n * HID + h4];
    v.x = fmaxf(v.x, 0.f);
    v.y = fmaxf(v.y, 0.f);
    v.z = fmaxf(v.z, 0.f);
    v.w = fmaxf(v.w, 0.f);
    float* sp = &sums[g * HID + h4];
    atomicAdd(sp + 0, v.x);
    atomicAdd(sp + 1, v.y);
    atomicAdd(sp + 2, v.z);
    atomicAdd(sp + 3, v.w);
}

__global__ void count_nodes(const int* __restrict__ batch, float* counts) {
    int n = blockIdx.x * 256 + threadIdx.x;
    if (n < N_NODES) atomicAdd(&counts[batch[n]], 1.0f);
}

// ---------------- head: out[g][o] = (sums[g]/cnt) @ Wout + bout ----------------
__global__ void final_gemm(const float* __restrict__ sums, const float* __restrict__ counts,
                           const float* __restrict__ Wout, const float* __restrict__ bout,
                           float* __restrict__ out) {
    int g = blockIdx.x;
    int o = threadIdx.x;   // 64
    __shared__ float p[HID];
    for (int k = o; k < HID; k += 64) p[k] = sums[g * HID + k];
    __syncthreads();
    float inv = 1.0f / fmaxf(counts[g], 1.0f);
    float acc = 0.f;
#pragma unroll 8
    for (int k = 0; k < HID; ++k)
        acc = fmaf(p[k], Wout[k * OUT_F + o], acc);
    out[g * OUT_F + o] = fmaf(inv, acc, bout[o]);
}

extern "C" void kernel_launch(void* const* d_in, const int* in_sizes, int n_in,
                              void* d_out, int out_size, void* d_ws, size_t ws_size,
                              hipStream_t stream) {
    const float* x     = (const float*)d_in[0];
    const int*   ei    = (const int*)d_in[1];
    const int*   batch = (const int*)d_in[2];
    const float* W1    = (const float*)d_in[3];
    const float* b1    = (const float*)d_in[4];
    const float* W2    = (const float*)d_in[5];
    const float* b2    = (const float*)d_in[6];
    const float* W3    = (const float*)d_in[7];
    const float* b3    = (const float*)d_in[8];
    const float* Wout  = (const float*)d_in[9];
    const float* bout  = (const float*)d_in[10];
    float* out = (float*)d_out;

    const int* src = ei;
    const int* dst = ei + N_EDGES;

    float* A      = (float*)d_ws;                 // N_NODES*HID
    float* B      = A + (size_t)N_NODES * HID;    // N_NODES*HID
    float* dinv   = B + (size_t)N_NODES * HID;    // N_NODES
    float* sums   = dinv + N_NODES;               // N_GRAPHS*HID
    float* counts = sums + N_GRAPHS * HID;        // N_GRAPHS

    // degrees -> dinv
    fill_deg<<<(N_NODES + 255) / 256, 256, 0, stream>>>(dinv);
    count_deg<<<N_EDGES / 256, 256, 0, stream>>>(dst, dinv);
    make_dinv<<<(N_NODES + 255) / 256, 256, 0, stream>>>(dinv);

    const int gemm_grid = N_NODES / 16;           // 6250, exact
    const int agg_grid  = N_NODES * 32 / 256;     // 12500, exact
    const int sc_grid   = N_EDGES / 8;            // 200000, exact

    // layer 1
    gemm<F_IN, false><<<gemm_grid, 256, 0, stream>>>(x, W1, A);
    init_agg<<<agg_grid, 256, 0, stream>>>(A, dinv, b1, B);
    scatter<<<sc_grid, 256, 0, stream>>>(A, src, dst, dinv, B);
    // layer 2
    gemm<HID, true><<<gemm_grid, 256, 0, stream>>>(B, W2, A);
    init_agg<<<agg_grid, 256, 0, stream>>>(A, dinv, b2, B);
    scatter<<<sc_grid, 256, 0, stream>>>(A, src, dst, dinv, B);
    // layer 3
    gemm<HID, true><<<gemm_grid, 256, 0, stream>>>(B, W3, A);
    init_agg<<<agg_grid, 256, 0, stream>>>(A, dinv, b3, B);
    scatter<<<sc_grid, 256, 0, stream>>>(A, src, dst, dinv, B);

    // pool + head
    zero_pool<<<(N_GRAPHS * HID + 255) / 256, 256, 0, stream>>>(sums, counts);
    pool<<<agg_grid, 256, 0, stream>>>(B, batch, sums);
    count_nodes<<<(N_NODES + 255) / 256, 256, 0, stream>>>(batch, counts);
    final_gemm<<<N_GRAPHS, 64, 0, stream>>>(sums, counts, Wout, bout, out);
}

// Round 3
// 897.390 us; speedup vs baseline: 9.6697x; 9.6697x over previous
//
#include <hip/hip_runtime.h>

#define N_NODES 100000
#define N_EDGES 1600000
#define N_GRAPHS 512
#define F_IN 20
#define HID 128
#define OUT_F 64
#define NB 391   // ceil(N_NODES/256)

// ---------------- CSR build ----------------
__global__ void zero_deg(int* deg) {
    int i = blockIdx.x * 256 + threadIdx.x;
    if (i < N_NODES) deg[i] = 0;
}

__global__ void zero_cursor(int* cur) {
    int i = blockIdx.x * 256 + threadIdx.x;
    if (i < N_NODES) cur[i] = 0;
}

__global__ void hist(const int* __restrict__ dst, int* deg) {
    int e = blockIdx.x * 256 + threadIdx.x;
    if (e < N_EDGES) atomicAdd(&deg[dst[e]], 1);
}

__global__ void scan1(const int* __restrict__ deg, int* rowtmp, int* partial) {
    __shared__ int lds[256];
    int t = threadIdx.x;
    int i = blockIdx.x * 256 + t;
    int v = (i < N_NODES) ? deg[i] : 0;
    lds[t] = v;
    __syncthreads();
    for (int off = 1; off < 256; off <<= 1) {
        int x = (t >= off) ? lds[t - off] : 0;
        __syncthreads();
        lds[t] += x;
        __syncthreads();
    }
    if (i < N_NODES) rowtmp[i] = lds[t] - v;
    if (t == 255) partial[blockIdx.x] = lds[255];
}

__global__ void scan2(int* partial) {
    __shared__ int lds[512];
    int t = threadIdx.x;
    int v = (t < NB) ? partial[t] : 0;
    lds[t] = v;
    __syncthreads();
    for (int off = 1; off < 512; off <<= 1) {
        int x = (t >= off) ? lds[t - off] : 0;
        __syncthreads();
        lds[t] += x;
        __syncthreads();
    }
    if (t < NB) partial[t] = lds[t] - v;
}

__global__ void scan3(const int* __restrict__ rowtmp, const int* __restrict__ partial,
                      int* row_st) {
    int i = blockIdx.x * 256 + threadIdx.x;
    if (i < N_NODES) row_st[i] = rowtmp[i] + partial[i >> 8];
    if (i == 0) row_st[N_NODES] = N_EDGES;
}

// fill CSR entries for dst nodes in [lo, hi)
__global__ void fill_chunk(const int* __restrict__ src, const int* __restrict__ dst,
                           const int* __restrict__ row_st, int* cursor,
                           int* __restrict__ csr, int lo, int hi, int cap) {
    int e = blockIdx.x * 256 + threadIdx.x;
    if (e >= N_EDGES) return;
    int d = dst[e];
    if (d < lo || d >= hi) return;
    int base = row_st[lo];
    int pos = row_st[d] - base + atomicAdd(&cursor[d], 1);
    if (pos < cap) csr[pos] = src[e];
}

// ---------------- GEMM: C[n] = dinv[n] * (act(A)[n] @ W),  C is T_scaled ----------------
template <int K, bool RELU>
__global__ __launch_bounds__(256) void gemm(const float* __restrict__ A,
                                            const float* __restrict__ W,
                                            const int* __restrict__ row_st,
                                            float* __restrict__ C) {
    constexpr int KC = (K > 64) ? 64 : K;
    __shared__ float Alds[16 * K];
    __shared__ float Wlds[KC * HID];
    const int t = threadIdx.x;
    const int node0 = blockIdx.x * 16;

    for (int idx = t; idx < 16 * K; idx += 256) {
        float v = A[node0 * K + idx];
        if (RELU) v = fmaxf(v, 0.0f);
        Alds[idx] = v;
    }

    const int h4 = (t & 31) * 4;
    const int g  = t >> 5;
    float4 acc0 = make_float4(0.f, 0.f, 0.f, 0.f);
    float4 acc1 = make_float4(0.f, 0.f, 0.f, 0.f);

    for (int k0 = 0; k0 < K; k0 += KC) {
        __syncthreads();
        for (int idx = t; idx < KC * HID; idx += 256)
            Wlds[idx] = W[k0 * HID + idx];
        __syncthreads();
#pragma unroll
        for (int kk = 0; kk < KC; ++kk) {
            float a0 = Alds[(g * 2) * K + k0 + kk];
            float a1 = Alds[(g * 2 + 1) * K + k0 + kk];
            float4 w = *(const float4*)&Wlds[kk * HID + h4];
            acc0.x = fmaf(a0, w.x, acc0.x);
            acc0.y = fmaf(a0, w.y, acc0.y);
            acc0.z = fmaf(a0, w.z, acc0.z);
            acc0.w = fmaf(a0, w.w, acc0.w);
            acc1.x = fmaf(a1, w.x, acc1.x);
            acc1.y = fmaf(a1, w.y, acc1.y);
            acc1.z = fmaf(a1, w.z, acc1.z);
            acc1.w = fmaf(a1, w.w, acc1.w);
        }
    }
    int na = node0 + g * 2;
    int nb = na + 1;
    float d0 = rsqrtf((float)(row_st[na + 1] - row_st[na] + 1));
    float d1 = rsqrtf((float)(row_st[nb + 1] - row_st[nb] + 1));
    acc0.x *= d0; acc0.y *= d0; acc0.z *= d0; acc0.w *= d0;
    acc1.x *= d1; acc1.y *= d1; acc1.z *= d1; acc1.w *= d1;
    *(float4*)&C[na * HID + h4] = acc0;
    *(float4*)&C[nb * HID + h4] = acc1;
}

// ---------------- gather for nodes [lo,hi): B[n] = b + dinv[n]*(T[n] + sum T[srcs]) ----------------
__global__ __launch_bounds__(256) void gather_range(const float* __restrict__ A,
                                                    const int* __restrict__ row_st,
                                                    const int* __restrict__ csr,
                                                    const float* __restrict__ bias,
                                                    float* __restrict__ B,
                                                    int lo, int hi) {
    int t = threadIdx.x;
    int n = lo + blockIdx.x * 8 + (t >> 5);
    if (n >= hi) return;
    int l = t & 31;
    int base = row_st[lo];
    int r0 = row_st[n], r1 = row_st[n + 1];
    float di = rsqrtf((float)(r1 - r0 + 1));
    const float4* Af = (const float4*)A;
    const int* cs = csr - base;
    float4 acc = Af[n * 32 + l];            // self term
    int r = r0;
    for (; r + 1 < r1; r += 2) {
        int s0 = cs[r];
        int s1 = cs[r + 1];
        float4 v0 = Af[s0 * 32 + l];
        float4 v1 = Af[s1 * 32 + l];
        acc.x += v0.x + v1.x;
        acc.y += v0.y + v1.y;
        acc.z += v0.z + v1.z;
        acc.w += v0.w + v1.w;
    }
    if (r < r1) {
        int s = cs[r];
        float4 v = Af[s * 32 + l];
        acc.x += v.x; acc.y += v.y; acc.z += v.z; acc.w += v.w;
    }
    float4 b4 = ((const float4*)bias)[l];
    float4 o;
    o.x = fmaf(di, acc.x, b4.x);
    o.y = fmaf(di, acc.y, b4.y);
    o.z = fmaf(di, acc.z, b4.z);
    o.w = fmaf(di, acc.w, b4.w);
    ((float4*)B)[n * 32 + l] = o;
}

// ---------------- atomic fallback (if workspace too small for CSR) ----------------
__global__ void init_B(const float* __restrict__ A, const int* __restrict__ row_st,
                       const float* __restrict__ bias, float* __restrict__ B) {
    int idx = blockIdx.x * 256 + threadIdx.x;   // N_NODES*32
    int n = idx >> 5, l = idx & 5 * 0 + (idx & 31);
    float di = rsqrtf((float)(row_st[n + 1] - row_st[n] + 1));
    float4 a = ((const float4*)A)[n * 32 + l];
    float4 b4 = ((const float4*)bias)[l];
    float4 o;
    o.x = fmaf(di, a.x, b4.x);
    o.y = fmaf(di, a.y, b4.y);
    o.z = fmaf(di, a.z, b4.z);
    o.w = fmaf(di, a.w, b4.w);
    ((float4*)B)[n * 32 + l] = o;
}

__global__ __launch_bounds__(256) void scatter_at(const float* __restrict__ A,
                                                  const int* __restrict__ src,
                                                  const int* __restrict__ dst,
                                                  const int* __restrict__ row_st,
                                                  float* B) {
    int t = threadIdx.x;
    int e = blockIdx.x * 8 + (t >> 5);
    int l = t & 31;
    int s = src[e];
    int d = dst[e];
    float dd = rsqrtf((float)(row_st[d + 1] - row_st[d] + 1));
    float4 a = ((const float4*)A)[s * 32 + l];
    float* bp = &B[d * HID + l * 4];
    atomicAdd(bp + 0, dd * a.x);
    atomicAdd(bp + 1, dd * a.y);
    atomicAdd(bp + 2, dd * a.z);
    atomicAdd(bp + 3, dd * a.w);
}

// ---------------- pooling / head ----------------
__global__ void zero_pool(float* sums, float* counts) {
    int i = blockIdx.x * 256 + threadIdx.x;
    if (i < N_GRAPHS * HID) sums[i] = 0.f;
    if (i < N_GRAPHS) counts[i] = 0.f;
}

__global__ __launch_bounds__(256) void pool(const float* __restrict__ B,
                                            const int* __restrict__ batch,
                                            float* sums) {
    int t = threadIdx.x;
    int grp = blockIdx.x * 8 + (t >> 5);
    int h4 = (t & 31) * 4;
    int n0 = grp * 8;
    if (n0 >= N_NODES) return;
    int cur = batch[n0];
    float4 acc = make_float4(0.f, 0.f, 0.f, 0.f);
    for (int k = 0; k < 8; ++k) {
        int n = n0 + k;
        if (n >= N_NODES) break;
        int g = batch[n];
        if (g != cur) {
            float* sp = &sums[cur * HID + h4];
            atomicAdd(sp + 0, acc.x); atomicAdd(sp + 1, acc.y);
            atomicAdd(sp + 2, acc.z); atomicAdd(sp + 3, acc.w);
            acc = make_float4(0.f, 0.f, 0.f, 0.f);
            cur = g;
        }
        float4 v = *(const float4*)&B[n * HID + h4];
        acc.x += fmaxf(v.x, 0.f);
        acc.y += fmaxf(v.y, 0.f);
        acc.z += fmaxf(v.z, 0.f);
        acc.w += fmaxf(v.w, 0.f);
    }
    float* sp = &sums[cur * HID + h4];
    atomicAdd(sp + 0, acc.x); atomicAdd(sp + 1, acc.y);
    atomicAdd(sp + 2, acc.z); atomicAdd(sp + 3, acc.w);
}

__global__ void count_nodes(const int* __restrict__ batch, float* counts) {
    int n = blockIdx.x * 256 + threadIdx.x;
    if (n < N_NODES) atomicAdd(&counts[batch[n]], 1.0f);
}

__global__ void final_gemm(const float* __restrict__ sums, const float* __restrict__ counts,
                           const float* __restrict__ Wout, const float* __restrict__ bout,
                           float* __restrict__ out) {
    int g = blockIdx.x;
    int o = threadIdx.x;   // 64
    __shared__ float p[HID];
    for (int k = o; k < HID; k += 64) p[k] = sums[g * HID + k];
    __syncthreads();
    float inv = 1.0f / fmaxf(counts[g], 1.0f);
    float acc = 0.f;
#pragma unroll 8
    for (int k = 0; k < HID; ++k)
        acc = fmaf(p[k], Wout[k * OUT_F + o], acc);
    out[g * OUT_F + o] = fmaf(inv, acc, bout[o]);
}

extern "C" void kernel_launch(void* const* d_in, const int* in_sizes, int n_in,
                              void* d_out, int out_size, void* d_ws, size_t ws_size,
                              hipStream_t stream) {
    const float* x     = (const float*)d_in[0];
    const int*   ei    = (const int*)d_in[1];
    const int*   batch = (const int*)d_in[2];
    const float* W1    = (const float*)d_in[3];
    const float* b1    = (const float*)d_in[4];
    const float* W2    = (const float*)d_in[5];
    const float* b2    = (const float*)d_in[6];
    const float* W3    = (const float*)d_in[7];
    const float* b3    = (const float*)d_in[8];
    const float* Wout  = (const float*)d_in[9];
    const float* bout  = (const float*)d_in[10];
    float* out = (float*)d_out;

    const int* src = ei;
    const int* dst = ei + N_EDGES;

    // core layout (103,064,196 B — matches round-1 proven footprint +4B)
    float* A      = (float*)d_ws;                        // 12.8M floats
    float* B      = A + (size_t)N_NODES * HID;           // 12.8M floats
    int*   row_st = (int*)(B + (size_t)N_NODES * HID);   // 100001 ints
    float* sums   = (float*)(row_st + N_NODES + 1);      // 65536
    float* counts = sums + N_GRAPHS * HID;               // 512
    int*   csr    = (int*)(counts + N_GRAPHS);           // whatever remains
    size_t used   = (size_t)((char*)csr - (char*)d_ws);
    long   cap    = (ws_size > used) ? (long)((ws_size - used) / 4) : 0;

    // overlays (dead regions)
    int* deg     = (int*)A;                              // A unused until gemm1
    int* rowtmp  = deg + N_NODES;
    int* partial = rowtmp + N_NODES;
    int* cursor  = ((int*)(B + (size_t)N_NODES * HID)) - N_NODES;  // B tail

    int n_chunks = 0;
    if      (cap >= (long)N_EDGES + 1024)        n_chunks = 1;
    else if (cap >= (long)N_EDGES / 2 + 16384)   n_chunks = 2;
    else if (cap >= (long)N_EDGES / 4 + 16384)   n_chunks = 4;
    else if (cap >= (long)N_EDGES / 8 + 16384)   n_chunks = 8;
    else if (cap >= (long)N_EDGES / 16 + 16384)  n_chunks = 16;

    const int gN = NB;            // 391
    const int gE = N_EDGES / 256; // 6250

    // degree + row_start (always)
    zero_deg<<<gN, 256, 0, stream>>>(deg);
    hist<<<gE, 256, 0, stream>>>(dst, deg);
    scan1<<<NB, 256, 0, stream>>>(deg, rowtmp, partial);
    scan2<<<1, 512, 0, stream>>>(partial);
    scan3<<<gN, 256, 0, stream>>>(rowtmp, partial, row_st);

    if (n_chunks == 1) {
        zero_cursor<<<gN, 256, 0, stream>>>(cursor);
        fill_chunk<<<gE, 256, 0, stream>>>(src, dst, row_st, cursor, csr, 0, N_NODES, (int)cap);
    }

    const int gemm_grid = N_NODES / 16;   // 6250

    for (int layer = 0; layer < 3; ++layer) {
        const float* Wl = (layer == 0) ? W1 : (layer == 1) ? W2 : W3;
        const float* bl = (layer == 0) ? b1 : (layer == 1) ? b2 : b3;
        if (layer == 0)
            gemm<F_IN, false><<<gemm_grid, 256, 0, stream>>>(x, Wl, row_st, A);
        else
            gemm<HID, true><<<gemm_grid, 256, 0, stream>>>(B, Wl, row_st, A);

        if (n_chunks == 1) {
            gather_range<<<N_NODES / 8, 256, 0, stream>>>(A, row_st, csr, bl, B, 0, N_NODES);
        } else if (n_chunks > 1) {
            zero_cursor<<<gN, 256, 0, stream>>>(cursor);
            int span = N_NODES / n_chunks;
            for (int q = 0; q < n_chunks; ++q) {
                int lo = q * span, hi = lo + span;
                fill_chunk<<<gE, 256, 0, stream>>>(src, dst, row_st, cursor, csr, lo, hi, (int)cap);
                int blocks = (span * 32 + 255) / 256;
                gather_range<<<blocks, 256, 0, stream>>>(A, row_st, csr, bl, B, lo, hi);
            }
        } else {
            init_B<<<N_NODES * 32 / 256, 256, 0, stream>>>(A, row_st, bl, B);
            scatter_at<<<N_EDGES / 8, 256, 0, stream>>>(A, src, dst, row_st, B);
        }
    }

    zero_pool<<<(N_GRAPHS * HID + 255) / 256, 256, 0, stream>>>(sums, counts);
    pool<<<(N_NODES / 8 + 7) / 8, 256, 0, stream>>>(B, batch, sums);
    count_nodes<<<gN, 256, 0, stream>>>(batch, counts);
    final_gemm<<<N_GRAPHS, 64, 0, stream>>>(sums, counts, Wout, bout, out);
}

// Round 4
// 671.023 us; speedup vs baseline: 12.9317x; 1.3373x over previous
//
#include <hip/hip_runtime.h>

#define N_NODES 100000
#define N_EDGES 1600000
#define N_GRAPHS 512
#define F_IN 20
#define HID 128
#define OUT_F 64

#define BUCKETS 256
#define SPAN 391        // ceil(N_NODES / BUCKETS); bucket b owns nodes [b*391, ...)
#define BCAP 7000       // per-bucket edge capacity: mean 6256, sigma ~79 -> 9.4 sigma
#define EPB 2048        // edges per partition block

// ---------------- zero sums/counts/cursors ----------------
__global__ void zero_all(float* sums, float* counts, int* cur256) {
    int i = blockIdx.x * 256 + threadIdx.x;   // grid 256 -> 65536 threads
    sums[i] = 0.f;                            // exactly N_GRAPHS*HID
    if (i < N_GRAPHS) counts[i] = 0.f;
    if (i >= 512 && i < 512 + BUCKETS) cur256[i - 512] = 0;
}

// ---------------- partition edges into 256 dst-range buckets ----------------
__global__ __launch_bounds__(256) void partition(const int* __restrict__ src,
                                                 const int* __restrict__ dst,
                                                 int2* __restrict__ bpairs,
                                                 int* cur256) {
    __shared__ int lcnt[BUCKETS];
    __shared__ int lbase[BUCKETS];
    int t = threadIdx.x;
    lcnt[t] = 0;
    __syncthreads();
    int base = blockIdx.x * EPB;
    int myb[8], mys[8], myd[8];
#pragma unroll
    for (int i = 0; i < 8; ++i) {
        int e = base + i * 256 + t;
        int b = -1, s = 0, d = 0;
        if (e < N_EDGES) {
            s = src[e]; d = dst[e];
            b = d / SPAN;
            atomicAdd(&lcnt[b], 1);
        }
        myb[i] = b; mys[i] = s; myd[i] = d;
    }
    __syncthreads();
    lbase[t] = atomicAdd(&cur256[t], lcnt[t]);
    lcnt[t] = 0;
    __syncthreads();
#pragma unroll
    for (int i = 0; i < 8; ++i) {
        int b = myb[i];
        if (b >= 0) {
            int p = lbase[b] + atomicAdd(&lcnt[b], 1);
            if (p < BCAP) bpairs[(size_t)b * BCAP + p] = make_int2(mys[i], myd[i]);
        }
    }
}

// ---------------- exclusive scan of bucket counts -> global bases ----------------
__global__ void scan_bbase(const int* __restrict__ cur256, int* bbase, int* row_st) {
    __shared__ int sc[BUCKETS];
    int t = threadIdx.x;
    int v = cur256[t];
    sc[t] = v;
    __syncthreads();
    for (int o = 1; o < BUCKETS; o <<= 1) {
        int x = (t >= o) ? sc[t - o] : 0;
        __syncthreads();
        sc[t] += x;
        __syncthreads();
    }
    bbase[t] = sc[t] - v;
    if (t == 0) row_st[N_NODES] = N_EDGES;
}

// ---------------- per-bucket CSR build: LDS hist -> LDS scan -> LDS-cursor fill ----------------
__global__ __launch_bounds__(256) void csr_build(const int2* __restrict__ bpairs,
                                                 const int* __restrict__ bcnt,
                                                 const int* __restrict__ bbase,
                                                 int* __restrict__ row_st,
                                                 int* __restrict__ csr) {
    __shared__ int ocnt[SPAN];
    __shared__ int sc[512];
    __shared__ int cur[SPAN];
    int b = blockIdx.x, t = threadIdx.x;
    int n0 = b * SPAN;
    int span = N_NODES - n0; if (span > SPAN) span = SPAN;
    for (int i = t; i < SPAN; i += 256) ocnt[i] = 0;
    __syncthreads();
    int n = bcnt[b];
    const int2* p = bpairs + (size_t)b * BCAP;
    for (int i = t; i < n; i += 256) atomicAdd(&ocnt[p[i].y - n0], 1);
    __syncthreads();
    sc[t]       = (t < span) ? ocnt[t] : 0;
    sc[t + 256] = (t + 256 < span) ? ocnt[t + 256] : 0;
    __syncthreads();
    for (int o = 1; o < 512; o <<= 1) {
        int a0 = (t >= o) ? sc[t - o] : 0;
        int a1 = sc[t + 256 - o];
        __syncthreads();
        sc[t] += a0;
        sc[t + 256] += a1;
        __syncthreads();
    }
    int base = bbase[b];
    for (int i = t; i < span; i += 256) {
        int start = sc[i] - ocnt[i];
        row_st[n0 + i] = base + start;
        cur[i] = start;
    }
    __syncthreads();
    for (int i = t; i < n; i += 256) {
        int2 e = p[i];
        int lp = atomicAdd(&cur[e.y - n0], 1);
        csr[base + lp] = e.x;
    }
}

// ---------------- layer-1 GEMM (K=20): C[n] = dinv[n] * (A[n] @ W) ----------------
template <int K, bool RELU>
__global__ __launch_bounds__(256) void gemm(const float* __restrict__ A,
                                            const float* __restrict__ W,
                                            const int* __restrict__ row_st,
                                            float* __restrict__ C) {
    constexpr int KC = (K > 64) ? 64 : K;
    __shared__ float Alds[16 * K];
    __shared__ float Wlds[KC * HID];
    const int t = threadIdx.x;
    const int node0 = blockIdx.x * 16;

    for (int idx = t; idx < 16 * K; idx += 256) {
        float v = A[node0 * K + idx];
        if (RELU) v = fmaxf(v, 0.0f);
        Alds[idx] = v;
    }

    const int h4 = (t & 31) * 4;
    const int g  = t >> 5;
    float4 acc0 = make_float4(0.f, 0.f, 0.f, 0.f);
    float4 acc1 = make_float4(0.f, 0.f, 0.f, 0.f);

    for (int k0 = 0; k0 < K; k0 += KC) {
        __syncthreads();
        for (int idx = t; idx < KC * HID; idx += 256)
            Wlds[idx] = W[k0 * HID + idx];
        __syncthreads();
#pragma unroll
        for (int kk = 0; kk < KC; ++kk) {
            float a0 = Alds[(g * 2) * K + k0 + kk];
            float a1 = Alds[(g * 2 + 1) * K + k0 + kk];
            float4 w = *(const float4*)&Wlds[kk * HID + h4];
            acc0.x = fmaf(a0, w.x, acc0.x);
            acc0.y = fmaf(a0, w.y, acc0.y);
            acc0.z = fmaf(a0, w.z, acc0.z);
            acc0.w = fmaf(a0, w.w, acc0.w);
            acc1.x = fmaf(a1, w.x, acc1.x);
            acc1.y = fmaf(a1, w.y, acc1.y);
            acc1.z = fmaf(a1, w.z, acc1.z);
            acc1.w = fmaf(a1, w.w, acc1.w);
        }
    }
    int na = node0 + g * 2;
    int nb = na + 1;
    float d0 = rsqrtf((float)(row_st[na + 1] - row_st[na] + 1));
    float d1 = rsqrtf((float)(row_st[nb + 1] - row_st[nb] + 1));
    acc0.x *= d0; acc0.y *= d0; acc0.z *= d0; acc0.w *= d0;
    acc1.x *= d1; acc1.y *= d1; acc1.z *= d1; acc1.w *= d1;
    *(float4*)&C[na * HID + h4] = acc0;
    *(float4*)&C[nb * HID + h4] = acc1;
}

// ---------------- layers-2/3 GEMM (K=128): register-blocked 64x128 tile ----------------
#define FMA4(as, wv, j) \
    acc[j].x = fmaf(as, wv.x, acc[j].x); \
    acc[j].y = fmaf(as, wv.y, acc[j].y); \
    acc[j].z = fmaf(as, wv.z, acc[j].z); \
    acc[j].w = fmaf(as, wv.w, acc[j].w);

__global__ __launch_bounds__(256) void gemm128(const float* __restrict__ In,
                                               const float* __restrict__ W,
                                               const int* __restrict__ row_st,
                                               float* __restrict__ C) {
    __shared__ float At[64 * HID];   // 32 KB, ReLU applied
    __shared__ float Wl[32 * HID];   // 16 KB
    const int t = threadIdx.x;
    const long node0 = (long)blockIdx.x * 64;
    const int cg = (t & 31) * 4;     // output cols cg..cg+3
    const int ng = (t >> 5) * 8;     // nodes ng..ng+7 within tile

    {   // stage A tile (guarded, zero-padded) with fused ReLU
        const float4* srcp = (const float4*)(In + node0 * HID);
        float4* dstp = (float4*)At;
        long limit = ((long)N_NODES * HID - node0 * HID) / 4;
        for (int i = t; i < 64 * 32; i += 256) {
            float4 v = (i < limit) ? srcp[i] : make_float4(0.f, 0.f, 0.f, 0.f);
            v.x = fmaxf(v.x, 0.f); v.y = fmaxf(v.y, 0.f);
            v.z = fmaxf(v.z, 0.f); v.w = fmaxf(v.w, 0.f);
            dstp[i] = v;
        }
    }

    float4 acc[8];
#pragma unroll
    for (int j = 0; j < 8; ++j) acc[j] = make_float4(0.f, 0.f, 0.f, 0.f);

    for (int kc = 0; kc < HID; kc += 32) {
        __syncthreads();
        {
            const float4* ws = (const float4*)(W + kc * HID);
            float4* wd = (float4*)Wl;
            for (int i = t; i < 32 * 32; i += 256) wd[i] = ws[i];
        }
        __syncthreads();
#pragma unroll
        for (int kk = 0; kk < 32; kk += 4) {
            float4 w0 = *(const float4*)&Wl[(kk + 0) * HID + cg];
            float4 w1 = *(const float4*)&Wl[(kk + 1) * HID + cg];
            float4 w2 = *(const float4*)&Wl[(kk + 2) * HID + cg];
            float4 w3 = *(const float4*)&Wl[(kk + 3) * HID + cg];
#pragma unroll
            for (int j = 0; j < 8; ++j) {
                float4 a = *(const float4*)&At[(ng + j) * HID + kc + kk];
                FMA4(a.x, w0, j)
                FMA4(a.y, w1, j)
                FMA4(a.z, w2, j)
                FMA4(a.w, w3, j)
            }
        }
    }

#pragma unroll
    for (int j = 0; j < 8; ++j) {
        long nn = node0 + ng + j;
        if (nn < N_NODES) {
            float d = rsqrtf((float)(row_st[nn + 1] - row_st[nn] + 1));
            float4 r = acc[j];
            r.x *= d; r.y *= d; r.z *= d; r.w *= d;
            *(float4*)&C[nn * HID + cg] = r;
        }
    }
}

// ---------------- gather: B[n] = bias + dinv[n]*(T[n] + sum T[srcs]) ----------------
__global__ __launch_bounds__(256) void gather_range(const float* __restrict__ A,
                                                    const int* __restrict__ row_st,
                                                    const int* __restrict__ csr,
                                                    const float* __restrict__ bias,
                                                    float* __restrict__ B) {
    int t = threadIdx.x;
    int n = blockIdx.x * 8 + (t >> 5);
    int l = t & 31;
    int r0 = row_st[n], r1 = row_st[n + 1];
    float di = rsqrtf((float)(r1 - r0 + 1));
    const float4* Af = (const float4*)A;
    float4 acc = Af[n * 32 + l];            // self term
    int r = r0;
    for (; r + 1 < r1; r += 2) {
        int s0 = csr[r];
        int s1 = csr[r + 1];
        float4 v0 = Af[s0 * 32 + l];
        float4 v1 = Af[s1 * 32 + l];
        acc.x += v0.x + v1.x;
        acc.y += v0.y + v1.y;
        acc.z += v0.z + v1.z;
        acc.w += v0.w + v1.w;
    }
    if (r < r1) {
        int s = csr[r];
        float4 v = Af[s * 32 + l];
        acc.x += v.x; acc.y += v.y; acc.z += v.z; acc.w += v.w;
    }
    float4 b4 = ((const float4*)bias)[l];
    float4 o;
    o.x = fmaf(di, acc.x, b4.x);
    o.y = fmaf(di, acc.y, b4.y);
    o.z = fmaf(di, acc.z, b4.z);
    o.w = fmaf(di, acc.w, b4.w);
    ((float4*)B)[n * 32 + l] = o;
}

// ---------------- pooling (fused node counting; batch is sorted) ----------------
__global__ __launch_bounds__(256) void pool(const float* __restrict__ B,
                                            const int* __restrict__ batch,
                                            float* sums, float* counts) {
    int t = threadIdx.x;
    int grp = blockIdx.x * 8 + (t >> 5);
    int h4 = (t & 31) * 4;
    int n0 = grp * 8;
    if (n0 >= N_NODES) return;
    int cur = batch[n0];
    int runlen = 0;
    float4 acc = make_float4(0.f, 0.f, 0.f, 0.f);
    for (int k = 0; k < 8; ++k) {
        int n = n0 + k;
        if (n >= N_NODES) break;
        int g = batch[n];
        if (g != cur) {
            float* sp = &sums[cur * HID + h4];
            atomicAdd(sp + 0, acc.x); atomicAdd(sp + 1, acc.y);
            atomicAdd(sp + 2, acc.z); atomicAdd(sp + 3, acc.w);
            if ((t & 31) == 0) atomicAdd(&counts[cur], (float)runlen);
            acc = make_float4(0.f, 0.f, 0.f, 0.f);
            runlen = 0;
            cur = g;
        }
        float4 v = *(const float4*)&B[n * HID + h4];
        acc.x += fmaxf(v.x, 0.f);
        acc.y += fmaxf(v.y, 0.f);
        acc.z += fmaxf(v.z, 0.f);
        acc.w += fmaxf(v.w, 0.f);
        ++runlen;
    }
    float* sp = &sums[cur * HID + h4];
    atomicAdd(sp + 0, acc.x); atomicAdd(sp + 1, acc.y);
    atomicAdd(sp + 2, acc.z); atomicAdd(sp + 3, acc.w);
    if ((t & 31) == 0) atomicAdd(&counts[cur], (float)runlen);
}

__global__ void final_gemm(const float* __restrict__ sums, const float* __restrict__ counts,
                           const float* __restrict__ Wout, const float* __restrict__ bout,
                           float* __restrict__ out) {
    int g = blockIdx.x;
    int o = threadIdx.x;   // 64
    __shared__ float p[HID];
    for (int k = o; k < HID; k += 64) p[k] = sums[g * HID + k];
    __syncthreads();
    float inv = 1.0f / fmaxf(counts[g], 1.0f);
    float acc = 0.f;
#pragma unroll 8
    for (int k = 0; k < HID; ++k)
        acc = fmaf(p[k], Wout[k * OUT_F + o], acc);
    out[g * OUT_F + o] = fmaf(inv, acc, bout[o]);
}

extern "C" void kernel_launch(void* const* d_in, const int* in_sizes, int n_in,
                              void* d_out, int out_size, void* d_ws, size_t ws_size,
                              hipStream_t stream) {
    const float* x     = (const float*)d_in[0];
    const int*   ei    = (const int*)d_in[1];
    const int*   batch = (const int*)d_in[2];
    const float* W1    = (const float*)d_in[3];
    const float* b1    = (const float*)d_in[4];
    const float* W2    = (const float*)d_in[5];
    const float* b2    = (const float*)d_in[6];
    const float* W3    = (const float*)d_in[7];
    const float* b3    = (const float*)d_in[8];
    const float* Wout  = (const float*)d_in[9];
    const float* bout  = (const float*)d_in[10];
    float* out = (float*)d_out;

    const int* src = ei;
    const int* dst = ei + N_EDGES;

    // workspace (total 109,466,244 B <= round-3-proven requirement)
    float* A      = (float*)d_ws;                        // 12.8M floats (bpairs overlay)
    float* B      = A + (size_t)N_NODES * HID;           // 12.8M floats
    int*   row_st = (int*)(B + (size_t)N_NODES * HID);   // 100001 ints
    float* sums   = (float*)(row_st + N_NODES + 1);      // 65536
    float* counts = sums + N_GRAPHS * HID;               // 512
    int*   csr    = (int*)(counts + N_GRAPHS);           // 1.6M ints
    int*   cur256 = csr + N_EDGES;                       // 256
    int*   bbase  = cur256 + BUCKETS;                    // 256

    int2* bpairs = (int2*)A;   // 256*7000*8B = 14.3 MB, dead before gemm layer 1

    // 1. zero sums/counts/bucket cursors
    zero_all<<<N_GRAPHS * HID / 256, 256, 0, stream>>>(sums, counts, cur256);
    // 2. CSR build: partition -> base scan -> per-bucket LDS build
    partition<<<(N_EDGES + EPB - 1) / EPB, 256, 0, stream>>>(src, dst, bpairs, cur256);
    scan_bbase<<<1, BUCKETS, 0, stream>>>(cur256, bbase, row_st);
    csr_build<<<BUCKETS, 256, 0, stream>>>(bpairs, cur256, bbase, row_st, csr);

    // 3. layers
    gemm<F_IN, false><<<N_NODES / 16, 256, 0, stream>>>(x, W1, row_st, A);
    gather_range<<<N_NODES / 8, 256, 0, stream>>>(A, row_st, csr, b1, B);
    gemm128<<<(N_NODES + 63) / 64, 256, 0, stream>>>(B, W2, row_st, A);
    gather_range<<<N_NODES / 8, 256, 0, stream>>>(A, row_st, csr, b2, B);
    gemm128<<<(N_NODES + 63) / 64, 256, 0, stream>>>(B, W3, row_st, A);
    gather_range<<<N_NODES / 8, 256, 0, stream>>>(A, row_st, csr, b3, B);

    // 4. pool + head
    pool<<<(N_NODES / 8 + 7) / 8, 256, 0, stream>>>(B, batch, sums, counts);
    final_gemm<<<N_GRAPHS, 64, 0, stream>>>(sums, counts, Wout, bout, out);
}

// Round 5
// 588.126 us; speedup vs baseline: 14.7544x; 1.1410x over previous
//
#include <hip/hip_runtime.h>

#define N_NODES 100000
#define N_EDGES 1600000
#define N_GRAPHS 512
#define F_IN 20
#define HID 128
#define OUT_F 64

#define BUCKETS 256
#define SPAN 391        // ceil(N_NODES / BUCKETS)
#define BCAP 7000       // per-bucket capacity (mean 6250, ~9 sigma headroom)
#define EPB 2048        // edges per partition block

// ---------------- zero sums/counts/cursors ----------------
__global__ void zero_all(float* sums, float* counts, int* cur256) {
    int i = blockIdx.x * 256 + threadIdx.x;
    sums[i] = 0.f;                            // exactly N_GRAPHS*HID
    if (i < N_GRAPHS) counts[i] = 0.f;
    if (i >= 512 && i < 512 + BUCKETS) cur256[i - 512] = 0;
}

// ---------------- partition edges into 256 dst-range buckets (packed) ----------------
// packed = (src << 9) | (dst - bucket*SPAN); src < 2^23, offset < 512
__global__ __launch_bounds__(256) void partition(const int* __restrict__ src,
                                                 const int* __restrict__ dst,
                                                 int* __restrict__ bpairs,
                                                 int* cur256) {
    __shared__ int lcnt[BUCKETS];
    __shared__ int lbase[BUCKETS];
    int t = threadIdx.x;
    lcnt[t] = 0;
    __syncthreads();
    int base = blockIdx.x * EPB;
    int myb[8], myp[8];
#pragma unroll
    for (int i = 0; i < 8; ++i) {
        int e = base + i * 256 + t;
        int b = -1, p = 0;
        if (e < N_EDGES) {
            int s = src[e], d = dst[e];
            b = d / SPAN;
            p = (s << 9) | (d - b * SPAN);
            atomicAdd(&lcnt[b], 1);
        }
        myb[i] = b; myp[i] = p;
    }
    __syncthreads();
    lbase[t] = atomicAdd(&cur256[t], lcnt[t]);
    lcnt[t] = 0;
    __syncthreads();
#pragma unroll
    for (int i = 0; i < 8; ++i) {
        int b = myb[i];
        if (b >= 0) {
            int p = lbase[b] + atomicAdd(&lcnt[b], 1);
            if (p < BCAP) bpairs[(size_t)b * BCAP + p] = myp[i];
        }
    }
}

// ---------------- exclusive scan of bucket counts ----------------
__global__ void scan_bbase(const int* __restrict__ cur256, int* bbase, int* row_st) {
    __shared__ int sc[BUCKETS];
    int t = threadIdx.x;
    int v = cur256[t];
    sc[t] = v;
    __syncthreads();
    for (int o = 1; o < BUCKETS; o <<= 1) {
        int x = (t >= o) ? sc[t - o] : 0;
        __syncthreads();
        sc[t] += x;
        __syncthreads();
    }
    bbase[t] = sc[t] - v;
    if (t == 0) row_st[N_NODES] = N_EDGES;
}

// ---------------- per-bucket CSR build ----------------
__global__ __launch_bounds__(256) void csr_build(const int* __restrict__ bpairs,
                                                 const int* __restrict__ bcnt,
                                                 const int* __restrict__ bbase,
                                                 int* __restrict__ row_st,
                                                 int* __restrict__ csr) {
    __shared__ int ocnt[SPAN];
    __shared__ int sc[512];
    __shared__ int cur[SPAN];
    int b = blockIdx.x, t = threadIdx.x;
    int n0 = b * SPAN;
    int span = N_NODES - n0; if (span > SPAN) span = SPAN;
    for (int i = t; i < SPAN; i += 256) ocnt[i] = 0;
    __syncthreads();
    int n = bcnt[b];
    const int* p = bpairs + (size_t)b * BCAP;
    for (int i = t; i < n; i += 256) atomicAdd(&ocnt[p[i] & 511], 1);
    __syncthreads();
    sc[t]       = (t < span) ? ocnt[t] : 0;
    sc[t + 256] = (t + 256 < span) ? ocnt[t + 256] : 0;
    __syncthreads();
    for (int o = 1; o < 512; o <<= 1) {
        int a0 = (t >= o) ? sc[t - o] : 0;
        int a1 = sc[t + 256 - o];
        __syncthreads();
        sc[t] += a0;
        sc[t + 256] += a1;
        __syncthreads();
    }
    int base = bbase[b];
    for (int i = t; i < span; i += 256) {
        int start = sc[i] - ocnt[i];
        row_st[n0 + i] = base + start;
        cur[i] = start;
    }
    __syncthreads();
    for (int i = t; i < n; i += 256) {
        int e = p[i];
        int lp = atomicAdd(&cur[e & 511], 1);
        csr[base + lp] = e >> 9;
    }
}

// ---------------- layer 1: Xs = dinv * x ----------------
__global__ void scale_x(const float* __restrict__ x, const int* __restrict__ row_st,
                        float* __restrict__ Xs) {
    int i = blockIdx.x * 256 + threadIdx.x;   // over N_NODES*F_IN
    if (i >= N_NODES * F_IN) return;
    int n = i / F_IN;
    float di = rsqrtf((float)(row_st[n + 1] - row_st[n] + 1));
    Xs[i] = di * x[i];
}

// ---------------- layer 1: Xagg[n] = dinv[n] * (Xs[n] + sum Xs[src]) ----------------
__global__ __launch_bounds__(256) void gather20(const float* __restrict__ Xs,
                                                const int* __restrict__ row_st,
                                                const int* __restrict__ csr,
                                                float* __restrict__ Xagg) {
    int t = threadIdx.x;
    if (t >= 240) return;
    int g = t / F_IN, f = t % F_IN;
    int n = blockIdx.x * 12 + g;
    if (n >= N_NODES) return;
    int r0 = row_st[n], r1 = row_st[n + 1];
    float acc = Xs[n * F_IN + f];   // self term
    int r = r0;
    for (; r + 3 < r1; r += 4) {
        int s0 = csr[r], s1 = csr[r + 1], s2 = csr[r + 2], s3 = csr[r + 3];
        float v0 = Xs[s0 * F_IN + f];
        float v1 = Xs[s1 * F_IN + f];
        float v2 = Xs[s2 * F_IN + f];
        float v3 = Xs[s3 * F_IN + f];
        acc += (v0 + v1) + (v2 + v3);
    }
    for (; r < r1; ++r) acc += Xs[csr[r] * F_IN + f];
    float di = rsqrtf((float)(r1 - r0 + 1));
    Xagg[n * F_IN + f] = di * acc;
}

// ---------------- layer 1 GEMM: h1 = Xagg @ W1 + b1 ----------------
__global__ __launch_bounds__(256) void gemm_l1(const float* __restrict__ A,
                                               const float* __restrict__ W,
                                               const float* __restrict__ bias,
                                               float* __restrict__ C) {
    __shared__ float Alds[16 * F_IN];
    __shared__ float Wlds[F_IN * HID];
    const int t = threadIdx.x;
    const int node0 = blockIdx.x * 16;

    for (int idx = t; idx < 16 * F_IN; idx += 256)
        Alds[idx] = A[node0 * F_IN + idx];
    for (int idx = t; idx < F_IN * HID; idx += 256)
        Wlds[idx] = W[idx];
    __syncthreads();

    const int h4 = (t & 31) * 4;
    const int g  = t >> 5;
    float4 b4 = *(const float4*)&bias[h4];
    float4 acc0 = b4;
    float4 acc1 = b4;
#pragma unroll
    for (int kk = 0; kk < F_IN; ++kk) {
        float a0 = Alds[(g * 2) * F_IN + kk];
        float a1 = Alds[(g * 2 + 1) * F_IN + kk];
        float4 w = *(const float4*)&Wlds[kk * HID + h4];
        acc0.x = fmaf(a0, w.x, acc0.x);
        acc0.y = fmaf(a0, w.y, acc0.y);
        acc0.z = fmaf(a0, w.z, acc0.z);
        acc0.w = fmaf(a0, w.w, acc0.w);
        acc1.x = fmaf(a1, w.x, acc1.x);
        acc1.y = fmaf(a1, w.y, acc1.y);
        acc1.z = fmaf(a1, w.z, acc1.z);
        acc1.w = fmaf(a1, w.w, acc1.w);
    }
    *(float4*)&C[(node0 + g * 2) * HID + h4]     = acc0;
    *(float4*)&C[(node0 + g * 2 + 1) * HID + h4] = acc1;
}

// ---------------- layers-2/3 GEMM (K=128): register-blocked 64x128 tile ----------------
#define FMA4(as, wv, j) \
    acc[j].x = fmaf(as, wv.x, acc[j].x); \
    acc[j].y = fmaf(as, wv.y, acc[j].y); \
    acc[j].z = fmaf(as, wv.z, acc[j].z); \
    acc[j].w = fmaf(as, wv.w, acc[j].w);

__global__ __launch_bounds__(256) void gemm128(const float* __restrict__ In,
                                               const float* __restrict__ W,
                                               const int* __restrict__ row_st,
                                               float* __restrict__ C) {
    __shared__ float At[64 * HID];   // 32 KB, ReLU applied
    __shared__ float Wl[32 * HID];   // 16 KB
    const int t = threadIdx.x;
    const long node0 = (long)blockIdx.x * 64;
    const int cg = (t & 31) * 4;
    const int ng = (t >> 5) * 8;

    {
        const float4* srcp = (const float4*)(In + node0 * HID);
        float4* dstp = (float4*)At;
        long limit = ((long)N_NODES * HID - node0 * HID) / 4;
        for (int i = t; i < 64 * 32; i += 256) {
            float4 v = (i < limit) ? srcp[i] : make_float4(0.f, 0.f, 0.f, 0.f);
            v.x = fmaxf(v.x, 0.f); v.y = fmaxf(v.y, 0.f);
            v.z = fmaxf(v.z, 0.f); v.w = fmaxf(v.w, 0.f);
            dstp[i] = v;
        }
    }

    float4 acc[8];
#pragma unroll
    for (int j = 0; j < 8; ++j) acc[j] = make_float4(0.f, 0.f, 0.f, 0.f);

    for (int kc = 0; kc < HID; kc += 32) {
        __syncthreads();
        {
            const float4* ws = (const float4*)(W + kc * HID);
            float4* wd = (float4*)Wl;
            for (int i = t; i < 32 * 32; i += 256) wd[i] = ws[i];
        }
        __syncthreads();
#pragma unroll
        for (int kk = 0; kk < 32; kk += 4) {
            float4 w0 = *(const float4*)&Wl[(kk + 0) * HID + cg];
            float4 w1 = *(const float4*)&Wl[(kk + 1) * HID + cg];
            float4 w2 = *(const float4*)&Wl[(kk + 2) * HID + cg];
            float4 w3 = *(const float4*)&Wl[(kk + 3) * HID + cg];
#pragma unroll
            for (int j = 0; j < 8; ++j) {
                float4 a = *(const float4*)&At[(ng + j) * HID + kc + kk];
                FMA4(a.x, w0, j)
                FMA4(a.y, w1, j)
                FMA4(a.z, w2, j)
                FMA4(a.w, w3, j)
            }
        }
    }

#pragma unroll
    for (int j = 0; j < 8; ++j) {
        long nn = node0 + ng + j;
        if (nn < N_NODES) {
            float d = rsqrtf((float)(row_st[nn + 1] - row_st[nn] + 1));
            float4 r = acc[j];
            r.x *= d; r.y *= d; r.z *= d; r.w *= d;
            *(float4*)&C[nn * HID + cg] = r;
        }
    }
}

// ---------------- gather (HID=128): B[n] = bias + dinv[n]*(T[n] + sum T[srcs]) ----------------
__global__ __launch_bounds__(256) void gather_range(const float* __restrict__ A,
                                                    const int* __restrict__ row_st,
                                                    const int* __restrict__ csr,
                                                    const float* __restrict__ bias,
                                                    float* __restrict__ B) {
    int t = threadIdx.x;
    int n = blockIdx.x * 8 + (t >> 5);
    int l = t & 31;
    int r0 = row_st[n], r1 = row_st[n + 1];
    float di = rsqrtf((float)(r1 - r0 + 1));
    const float4* Af = (const float4*)A;
    float4 acc = Af[n * 32 + l];            // self term
    int r = r0;
    for (; r + 3 < r1; r += 4) {
        int s0 = csr[r];
        int s1 = csr[r + 1];
        int s2 = csr[r + 2];
        int s3 = csr[r + 3];
        float4 v0 = Af[s0 * 32 + l];
        float4 v1 = Af[s1 * 32 + l];
        float4 v2 = Af[s2 * 32 + l];
        float4 v3 = Af[s3 * 32 + l];
        acc.x += (v0.x + v1.x) + (v2.x + v3.x);
        acc.y += (v0.y + v1.y) + (v2.y + v3.y);
        acc.z += (v0.z + v1.z) + (v2.z + v3.z);
        acc.w += (v0.w + v1.w) + (v2.w + v3.w);
    }
    for (; r < r1; ++r) {
        int s = csr[r];
        float4 v = Af[s * 32 + l];
        acc.x += v.x; acc.y += v.y; acc.z += v.z; acc.w += v.w;
    }
    float4 b4 = ((const float4*)bias)[l];
    float4 o;
    o.x = fmaf(di, acc.x, b4.x);
    o.y = fmaf(di, acc.y, b4.y);
    o.z = fmaf(di, acc.z, b4.z);
    o.w = fmaf(di, acc.w, b4.w);
    ((float4*)B)[n * 32 + l] = o;
}

// ---------------- pooling (fused node counting; batch is sorted) ----------------
__global__ __launch_bounds__(256) void pool(const float* __restrict__ B,
                                            const int* __restrict__ batch,
                                            float* sums, float* counts) {
    int t = threadIdx.x;
    int grp = blockIdx.x * 8 + (t >> 5);
    int h4 = (t & 31) * 4;
    int n0 = grp * 8;
    if (n0 >= N_NODES) return;
    int cur = batch[n0];
    int runlen = 0;
    float4 acc = make_float4(0.f, 0.f, 0.f, 0.f);
    for (int k = 0; k < 8; ++k) {
        int n = n0 + k;
        if (n >= N_NODES) break;
        int g = batch[n];
        if (g != cur) {
            float* sp = &sums[cur * HID + h4];
            atomicAdd(sp + 0, acc.x); atomicAdd(sp + 1, acc.y);
            atomicAdd(sp + 2, acc.z); atomicAdd(sp + 3, acc.w);
            if ((t & 31) == 0) atomicAdd(&counts[cur], (float)runlen);
            acc = make_float4(0.f, 0.f, 0.f, 0.f);
            runlen = 0;
            cur = g;
        }
        float4 v = *(const float4*)&B[n * HID + h4];
        acc.x += fmaxf(v.x, 0.f);
        acc.y += fmaxf(v.y, 0.f);
        acc.z += fmaxf(v.z, 0.f);
        acc.w += fmaxf(v.w, 0.f);
        ++runlen;
    }
    float* sp = &sums[cur * HID + h4];
    atomicAdd(sp + 0, acc.x); atomicAdd(sp + 1, acc.y);
    atomicAdd(sp + 2, acc.z); atomicAdd(sp + 3, acc.w);
    if ((t & 31) == 0) atomicAdd(&counts[cur], (float)runlen);
}

__global__ void final_gemm(const float* __restrict__ sums, const float* __restrict__ counts,
                           const float* __restrict__ Wout, const float* __restrict__ bout,
                           float* __restrict__ out) {
    int g = blockIdx.x;
    int o = threadIdx.x;   // 64
    __shared__ float p[HID];
    for (int k = o; k < HID; k += 64) p[k] = sums[g * HID + k];
    __syncthreads();
    float inv = 1.0f / fmaxf(counts[g], 1.0f);
    float acc = 0.f;
#pragma unroll 8
    for (int k = 0; k < HID; ++k)
        acc = fmaf(p[k], Wout[k * OUT_F + o], acc);
    out[g * OUT_F + o] = fmaf(inv, acc, bout[o]);
}

extern "C" void kernel_launch(void* const* d_in, const int* in_sizes, int n_in,
                              void* d_out, int out_size, void* d_ws, size_t ws_size,
                              hipStream_t stream) {
    const float* x     = (const float*)d_in[0];
    const int*   ei    = (const int*)d_in[1];
    const int*   batch = (const int*)d_in[2];
    const float* W1    = (const float*)d_in[3];
    const float* b1    = (const float*)d_in[4];
    const float* W2    = (const float*)d_in[5];
    const float* b2    = (const float*)d_in[6];
    const float* W3    = (const float*)d_in[7];
    const float* b3    = (const float*)d_in[8];
    const float* Wout  = (const float*)d_in[9];
    const float* bout  = (const float*)d_in[10];
    float* out = (float*)d_out;

    const int* src = ei;
    const int* dst = ei + N_EDGES;

    // workspace (same proven footprint as round 4)
    float* A      = (float*)d_ws;                        // 12.8M floats
    float* B      = A + (size_t)N_NODES * HID;           // 12.8M floats
    int*   row_st = (int*)(B + (size_t)N_NODES * HID);   // 100001 ints
    float* sums   = (float*)(row_st + N_NODES + 1);      // 65536
    float* counts = sums + N_GRAPHS * HID;               // 512
    int*   csr    = (int*)(counts + N_GRAPHS);           // 1.6M ints
    int*   cur256 = csr + N_EDGES;                       // 256
    int*   bbase  = cur256 + BUCKETS;                    // 256

    int* bpairs = (int*)A;              // 256*7000*4 B = 7.2 MB overlay, dead after csr_build
    float* Xs   = A;                    // N_NODES*F_IN (reuses A after csr_build)
    float* Xagg = A + N_NODES * F_IN;   // N_NODES*F_IN

    // 1. zero + CSR build
    zero_all<<<N_GRAPHS * HID / 256, 256, 0, stream>>>(sums, counts, cur256);
    partition<<<(N_EDGES + EPB - 1) / EPB, 256, 0, stream>>>(src, dst, bpairs, cur256);
    scan_bbase<<<1, BUCKETS, 0, stream>>>(cur256, bbase, row_st);
    csr_build<<<BUCKETS, 256, 0, stream>>>(bpairs, cur256, bbase, row_st, csr);

    // 2. layer 1: aggregate in F_IN=20, then transform
    scale_x<<<(N_NODES * F_IN + 255) / 256, 256, 0, stream>>>(x, row_st, Xs);
    gather20<<<(N_NODES + 11) / 12, 256, 0, stream>>>(Xs, row_st, csr, Xagg);
    gemm_l1<<<N_NODES / 16, 256, 0, stream>>>(Xagg, W1, b1, B);

    // 3. layers 2/3: transform (ReLU fused) then aggregate
    gemm128<<<(N_NODES + 63) / 64, 256, 0, stream>>>(B, W2, row_st, A);
    gather_range<<<N_NODES / 8, 256, 0, stream>>>(A, row_st, csr, b2, B);
    gemm128<<<(N_NODES + 63) / 64, 256, 0, stream>>>(B, W3, row_st, A);
    gather_range<<<N_NODES / 8, 256, 0, stream>>>(A, row_st, csr, b3, B);

    // 4. pool + head
    pool<<<(N_NODES / 8 + 7) / 8, 256, 0, stream>>>(B, batch, sums, counts);
    final_gemm<<<N_GRAPHS, 64, 0, stream>>>(sums, counts, Wout, bout, out);
}

// Round 6
// 487.794 us; speedup vs baseline: 17.7892x; 1.2057x over previous
//
#include <hip/hip_runtime.h>
#include <hip/hip_fp16.h>

#define N_NODES 100000
#define N_EDGES 1600000
#define N_GRAPHS 512
#define F_IN 20
#define HID 128
#define OUT_F 64

#define BUCKETS 256
#define SPAN 391        // ceil(N_NODES / BUCKETS)
#define BCAP 7000       // per-bucket capacity (mean 6250, ~9 sigma headroom)
#define EPB 2048        // edges per partition block

__device__ inline float4 h4_to_f4(uint2 u) {
    __half2 h0 = *(__half2*)&u.x;
    __half2 h1 = *(__half2*)&u.y;
    float2 f0 = __half22float2(h0);
    float2 f1 = __half22float2(h1);
    return make_float4(f0.x, f0.y, f1.x, f1.y);
}

// ---------------- zero sums/counts/cursors ----------------
__global__ void zero_all(float* sums, float* counts, int* cur256) {
    int i = blockIdx.x * 256 + threadIdx.x;
    sums[i] = 0.f;                            // exactly N_GRAPHS*HID
    if (i < N_GRAPHS) counts[i] = 0.f;
    if (i >= 512 && i < 512 + BUCKETS) cur256[i - 512] = 0;
}

// ---------------- partition edges into 256 dst-range buckets (packed) ----------------
// packed = (src << 9) | (dst - bucket*SPAN)
__global__ __launch_bounds__(256) void partition(const int* __restrict__ src,
                                                 const int* __restrict__ dst,
                                                 int* __restrict__ bpairs,
                                                 int* cur256) {
    __shared__ int lcnt[BUCKETS];
    __shared__ int lbase[BUCKETS];
    int t = threadIdx.x;
    lcnt[t] = 0;
    __syncthreads();
    int base = blockIdx.x * EPB;
    int myb[8], myp[8];
#pragma unroll
    for (int i = 0; i < 8; ++i) {
        int e = base + i * 256 + t;
        int b = -1, p = 0;
        if (e < N_EDGES) {
            int s = src[e], d = dst[e];
            b = d / SPAN;
            p = (s << 9) | (d - b * SPAN);
            atomicAdd(&lcnt[b], 1);
        }
        myb[i] = b; myp[i] = p;
    }
    __syncthreads();
    lbase[t] = atomicAdd(&cur256[t], lcnt[t]);
    lcnt[t] = 0;
    __syncthreads();
#pragma unroll
    for (int i = 0; i < 8; ++i) {
        int b = myb[i];
        if (b >= 0) {
            int p = lbase[b] + atomicAdd(&lcnt[b], 1);
            if (p < BCAP) bpairs[(size_t)b * BCAP + p] = myp[i];
        }
    }
}

// ---------------- exclusive scan of bucket counts ----------------
__global__ void scan_bbase(const int* __restrict__ cur256, int* bbase, int* row_st) {
    __shared__ int sc[BUCKETS];
    int t = threadIdx.x;
    int v = cur256[t];
    sc[t] = v;
    __syncthreads();
    for (int o = 1; o < BUCKETS; o <<= 1) {
        int x = (t >= o) ? sc[t - o] : 0;
        __syncthreads();
        sc[t] += x;
        __syncthreads();
    }
    bbase[t] = sc[t] - v;
    if (t == 0) row_st[N_NODES] = N_EDGES;
}

// ---------------- per-bucket CSR build ----------------
__global__ __launch_bounds__(256) void csr_build(const int* __restrict__ bpairs,
                                                 const int* __restrict__ bcnt,
                                                 const int* __restrict__ bbase,
                                                 int* __restrict__ row_st,
                                                 int* __restrict__ csr) {
    __shared__ int ocnt[SPAN];
    __shared__ int sc[512];
    __shared__ int cur[SPAN];
    int b = blockIdx.x, t = threadIdx.x;
    int n0 = b * SPAN;
    int span = N_NODES - n0; if (span > SPAN) span = SPAN;
    for (int i = t; i < SPAN; i += 256) ocnt[i] = 0;
    __syncthreads();
    int n = bcnt[b];
    const int* p = bpairs + (size_t)b * BCAP;
    for (int i = t; i < n; i += 256) atomicAdd(&ocnt[p[i] & 511], 1);
    __syncthreads();
    sc[t]       = (t < span) ? ocnt[t] : 0;
    sc[t + 256] = (t + 256 < span) ? ocnt[t + 256] : 0;
    __syncthreads();
    for (int o = 1; o < 512; o <<= 1) {
        int a0 = (t >= o) ? sc[t - o] : 0;
        int a1 = sc[t + 256 - o];
        __syncthreads();
        sc[t] += a0;
        sc[t + 256] += a1;
        __syncthreads();
    }
    int base = bbase[b];
    for (int i = t; i < span; i += 256) {
        int start = sc[i] - ocnt[i];
        row_st[n0 + i] = base + start;
        cur[i] = start;
    }
    __syncthreads();
    for (int i = t; i < n; i += 256) {
        int e = p[i];
        int lp = atomicAdd(&cur[e & 511], 1);
        csr[base + lp] = e >> 9;
    }
}

// ---------------- layer 1: Xs = fp16(dinv * x) ----------------
__global__ void scale_x(const float* __restrict__ x, const int* __restrict__ row_st,
                        __half* __restrict__ Xs) {
    int i = blockIdx.x * 256 + threadIdx.x;
    if (i >= N_NODES * F_IN) return;
    int n = i / F_IN;
    float di = rsqrtf((float)(row_st[n + 1] - row_st[n] + 1));
    Xs[i] = __float2half(di * x[i]);
}

// ---------------- layer 1: Xagg[n] = dinv[n] * (Xs[n] + sum Xs[src]) ----------------
__global__ __launch_bounds__(256) void gather20(const __half* __restrict__ Xs,
                                                const int* __restrict__ row_st,
                                                const int* __restrict__ csr,
                                                float* __restrict__ Xagg) {
    int t = threadIdx.x;
    if (t >= 240) return;
    int g = t / F_IN, f = t % F_IN;
    int n = blockIdx.x * 12 + g;
    if (n >= N_NODES) return;
    int r0 = row_st[n], r1 = row_st[n + 1];
    float acc = __half2float(Xs[n * F_IN + f]);   // self term
    int r = r0;
    for (; r + 3 < r1; r += 4) {
        int s0 = csr[r], s1 = csr[r + 1], s2 = csr[r + 2], s3 = csr[r + 3];
        float v0 = __half2float(Xs[s0 * F_IN + f]);
        float v1 = __half2float(Xs[s1 * F_IN + f]);
        float v2 = __half2float(Xs[s2 * F_IN + f]);
        float v3 = __half2float(Xs[s3 * F_IN + f]);
        acc += (v0 + v1) + (v2 + v3);
    }
    for (; r < r1; ++r) acc += __half2float(Xs[csr[r] * F_IN + f]);
    float di = rsqrtf((float)(r1 - r0 + 1));
    Xagg[n * F_IN + f] = di * acc;
}

// ---------------- layer 1 GEMM: h1 = Xagg @ W1 + b1 (fp32 out) ----------------
__global__ __launch_bounds__(256) void gemm_l1(const float* __restrict__ A,
                                               const float* __restrict__ W,
                                               const float* __restrict__ bias,
                                               float* __restrict__ C) {
    __shared__ float Alds[16 * F_IN];
    __shared__ float Wlds[F_IN * HID];
    const int t = threadIdx.x;
    const int node0 = blockIdx.x * 16;

    for (int idx = t; idx < 16 * F_IN; idx += 256)
        Alds[idx] = A[node0 * F_IN + idx];
    for (int idx = t; idx < F_IN * HID; idx += 256)
        Wlds[idx] = W[idx];
    __syncthreads();

    const int h4 = (t & 31) * 4;
    const int g  = t >> 5;
    float4 b4 = *(const float4*)&bias[h4];
    float4 acc0 = b4;
    float4 acc1 = b4;
#pragma unroll
    for (int kk = 0; kk < F_IN; ++kk) {
        float a0 = Alds[(g * 2) * F_IN + kk];
        float a1 = Alds[(g * 2 + 1) * F_IN + kk];
        float4 w = *(const float4*)&Wlds[kk * HID + h4];
        acc0.x = fmaf(a0, w.x, acc0.x);
        acc0.y = fmaf(a0, w.y, acc0.y);
        acc0.z = fmaf(a0, w.z, acc0.z);
        acc0.w = fmaf(a0, w.w, acc0.w);
        acc1.x = fmaf(a1, w.x, acc1.x);
        acc1.y = fmaf(a1, w.y, acc1.y);
        acc1.z = fmaf(a1, w.z, acc1.z);
        acc1.w = fmaf(a1, w.w, acc1.w);
    }
    *(float4*)&C[(node0 + g * 2) * HID + h4]     = acc0;
    *(float4*)&C[(node0 + g * 2 + 1) * HID + h4] = acc1;
}

// ---------------- layers-2/3 GEMM (K=128): fp32 in, fp16 out (scaled) ----------------
#define FMA4(as, wv, j) \
    acc[j].x = fmaf(as, wv.x, acc[j].x); \
    acc[j].y = fmaf(as, wv.y, acc[j].y); \
    acc[j].z = fmaf(as, wv.z, acc[j].z); \
    acc[j].w = fmaf(as, wv.w, acc[j].w);

__global__ __launch_bounds__(256) void gemm128(const float* __restrict__ In,
                                               const float* __restrict__ W,
                                               const int* __restrict__ row_st,
                                               __half* __restrict__ C) {
    __shared__ float At[64 * HID];   // 32 KB, ReLU applied
    __shared__ float Wl[32 * HID];   // 16 KB
    const int t = threadIdx.x;
    const long node0 = (long)blockIdx.x * 64;
    const int cg = (t & 31) * 4;
    const int ng = (t >> 5) * 8;

    {
        const float4* srcp = (const float4*)(In + node0 * HID);
        float4* dstp = (float4*)At;
        long limit = ((long)N_NODES * HID - node0 * HID) / 4;
        for (int i = t; i < 64 * 32; i += 256) {
            float4 v = (i < limit) ? srcp[i] : make_float4(0.f, 0.f, 0.f, 0.f);
            v.x = fmaxf(v.x, 0.f); v.y = fmaxf(v.y, 0.f);
            v.z = fmaxf(v.z, 0.f); v.w = fmaxf(v.w, 0.f);
            dstp[i] = v;
        }
    }

    float4 acc[8];
#pragma unroll
    for (int j = 0; j < 8; ++j) acc[j] = make_float4(0.f, 0.f, 0.f, 0.f);

    for (int kc = 0; kc < HID; kc += 32) {
        __syncthreads();
        {
            const float4* ws = (const float4*)(W + kc * HID);
            float4* wd = (float4*)Wl;
            for (int i = t; i < 32 * 32; i += 256) wd[i] = ws[i];
        }
        __syncthreads();
#pragma unroll
        for (int kk = 0; kk < 32; kk += 4) {
            float4 w0 = *(const float4*)&Wl[(kk + 0) * HID + cg];
            float4 w1 = *(const float4*)&Wl[(kk + 1) * HID + cg];
            float4 w2 = *(const float4*)&Wl[(kk + 2) * HID + cg];
            float4 w3 = *(const float4*)&Wl[(kk + 3) * HID + cg];
#pragma unroll
            for (int j = 0; j < 8; ++j) {
                float4 a = *(const float4*)&At[(ng + j) * HID + kc + kk];
                FMA4(a.x, w0, j)
                FMA4(a.y, w1, j)
                FMA4(a.z, w2, j)
                FMA4(a.w, w3, j)
            }
        }
    }

#pragma unroll
    for (int j = 0; j < 8; ++j) {
        long nn = node0 + ng + j;
        if (nn < N_NODES) {
            float d = rsqrtf((float)(row_st[nn + 1] - row_st[nn] + 1));
            __half2 h0 = __floats2half2_rn(acc[j].x * d, acc[j].y * d);
            __half2 h1 = __floats2half2_rn(acc[j].z * d, acc[j].w * d);
            uint2 u;
            u.x = *(unsigned int*)&h0;
            u.y = *(unsigned int*)&h1;
            ((uint2*)C)[nn * 32 + (cg >> 2)] = u;
        }
    }
}

// ---------------- gather (fp16 rows): B[n] = bias + dinv[n]*(T[n] + sum T[srcs]) ----------------
__global__ __launch_bounds__(256) void gather_range(const __half* __restrict__ A,
                                                    const int* __restrict__ row_st,
                                                    const int* __restrict__ csr,
                                                    const float* __restrict__ bias,
                                                    float* __restrict__ B) {
    int t = threadIdx.x;
    int n = blockIdx.x * 8 + (t >> 5);
    int l = t & 31;
    int r0 = row_st[n], r1 = row_st[n + 1];
    float di = rsqrtf((float)(r1 - r0 + 1));
    const uint2* Af = (const uint2*)A;   // 4 halves per lane
    float4 acc = h4_to_f4(Af[n * 32 + l]);   // self term
    int r = r0;
    for (; r + 3 < r1; r += 4) {
        int s0 = csr[r];
        int s1 = csr[r + 1];
        int s2 = csr[r + 2];
        int s3 = csr[r + 3];
        float4 v0 = h4_to_f4(Af[s0 * 32 + l]);
        float4 v1 = h4_to_f4(Af[s1 * 32 + l]);
        float4 v2 = h4_to_f4(Af[s2 * 32 + l]);
        float4 v3 = h4_to_f4(Af[s3 * 32 + l]);
        acc.x += (v0.x + v1.x) + (v2.x + v3.x);
        acc.y += (v0.y + v1.y) + (v2.y + v3.y);
        acc.z += (v0.z + v1.z) + (v2.z + v3.z);
        acc.w += (v0.w + v1.w) + (v2.w + v3.w);
    }
    for (; r < r1; ++r) {
        float4 v = h4_to_f4(Af[csr[r] * 32 + l]);
        acc.x += v.x; acc.y += v.y; acc.z += v.z; acc.w += v.w;
    }
    float4 b4 = ((const float4*)bias)[l];
    float4 o;
    o.x = fmaf(di, acc.x, b4.x);
    o.y = fmaf(di, acc.y, b4.y);
    o.z = fmaf(di, acc.z, b4.z);
    o.w = fmaf(di, acc.w, b4.w);
    ((float4*)B)[n * 32 + l] = o;
}

// ---------------- pooling (fused node counting; batch is sorted) ----------------
__global__ __launch_bounds__(256) void pool(const float* __restrict__ B,
                                            const int* __restrict__ batch,
                                            float* sums, float* counts) {
    int t = threadIdx.x;
    int grp = blockIdx.x * 8 + (t >> 5);
    int h4 = (t & 31) * 4;
    int n0 = grp * 8;
    if (n0 >= N_NODES) return;
    int cur = batch[n0];
    int runlen = 0;
    float4 acc = make_float4(0.f, 0.f, 0.f, 0.f);
    for (int k = 0; k < 8; ++k) {
        int n = n0 + k;
        if (n >= N_NODES) break;
        int g = batch[n];
        if (g != cur) {
            float* sp = &sums[cur * HID + h4];
            atomicAdd(sp + 0, acc.x); atomicAdd(sp + 1, acc.y);
            atomicAdd(sp + 2, acc.z); atomicAdd(sp + 3, acc.w);
            if ((t & 31) == 0) atomicAdd(&counts[cur], (float)runlen);
            acc = make_float4(0.f, 0.f, 0.f, 0.f);
            runlen = 0;
            cur = g;
        }
        float4 v = *(const float4*)&B[n * HID + h4];
        acc.x += fmaxf(v.x, 0.f);
        acc.y += fmaxf(v.y, 0.f);
        acc.z += fmaxf(v.z, 0.f);
        acc.w += fmaxf(v.w, 0.f);
        ++runlen;
    }
    float* sp = &sums[cur * HID + h4];
    atomicAdd(sp + 0, acc.x); atomicAdd(sp + 1, acc.y);
    atomicAdd(sp + 2, acc.z); atomicAdd(sp + 3, acc.w);
    if ((t & 31) == 0) atomicAdd(&counts[cur], (float)runlen);
}

__global__ void final_gemm(const float* __restrict__ sums, const float* __restrict__ counts,
                           const float* __restrict__ Wout, const float* __restrict__ bout,
                           float* __restrict__ out) {
    int g = blockIdx.x;
    int o = threadIdx.x;   // 64
    __shared__ float p[HID];
    for (int k = o; k < HID; k += 64) p[k] = sums[g * HID + k];
    __syncthreads();
    float inv = 1.0f / fmaxf(counts[g], 1.0f);
    float acc = 0.f;
#pragma unroll 8
    for (int k = 0; k < HID; ++k)
        acc = fmaf(p[k], Wout[k * OUT_F + o], acc);
    out[g * OUT_F + o] = fmaf(inv, acc, bout[o]);
}

extern "C" void kernel_launch(void* const* d_in, const int* in_sizes, int n_in,
                              void* d_out, int out_size, void* d_ws, size_t ws_size,
                              hipStream_t stream) {
    const float* x     = (const float*)d_in[0];
    const int*   ei    = (const int*)d_in[1];
    const int*   batch = (const int*)d_in[2];
    const float* W1    = (const float*)d_in[3];
    const float* b1    = (const float*)d_in[4];
    const float* W2    = (const float*)d_in[5];
    const float* b2    = (const float*)d_in[6];
    const float* W3    = (const float*)d_in[7];
    const float* b3    = (const float*)d_in[8];
    const float* Wout  = (const float*)d_in[9];
    const float* bout  = (const float*)d_in[10];
    float* out = (float*)d_out;

    const int* src = ei;
    const int* dst = ei + N_EDGES;

    // workspace (same proven footprint as rounds 4/5)
    float* A      = (float*)d_ws;                        // 12.8M floats
    float* B      = A + (size_t)N_NODES * HID;           // 12.8M floats
    int*   row_st = (int*)(B + (size_t)N_NODES * HID);   // 100001 ints
    float* sums   = (float*)(row_st + N_NODES + 1);      // 65536
    float* counts = sums + N_GRAPHS * HID;               // 512
    int*   csr    = (int*)(counts + N_GRAPHS);           // 1.6M ints
    int*   cur256 = csr + N_EDGES;                       // 256
    int*   bbase  = cur256 + BUCKETS;                    // 256

    int*    bpairs = (int*)A;             // 7.2 MB overlay, dead after csr_build
    __half* Xs     = (__half*)A;          // N_NODES*F_IN halves (4 MB)
    float*  Xagg   = A + 1000000;         // N_NODES*F_IN floats, after Xs
    __half* T      = (__half*)A;          // fp16 message table (25.6 MB), overlays A

    // 1. zero + CSR build
    zero_all<<<N_GRAPHS * HID / 256, 256, 0, stream>>>(sums, counts, cur256);
    partition<<<(N_EDGES + EPB - 1) / EPB, 256, 0, stream>>>(src, dst, bpairs, cur256);
    scan_bbase<<<1, BUCKETS, 0, stream>>>(cur256, bbase, row_st);
    csr_build<<<BUCKETS, 256, 0, stream>>>(bpairs, cur256, bbase, row_st, csr);

    // 2. layer 1: aggregate in F_IN=20 (fp16 rows), then transform
    scale_x<<<(N_NODES * F_IN + 255) / 256, 256, 0, stream>>>(x, row_st, Xs);
    gather20<<<(N_NODES + 11) / 12, 256, 0, stream>>>(Xs, row_st, csr, Xagg);
    gemm_l1<<<N_NODES / 16, 256, 0, stream>>>(Xagg, W1, b1, B);

    // 3. layers 2/3: transform (ReLU fused, fp16 out) then aggregate
    gemm128<<<(N_NODES + 63) / 64, 256, 0, stream>>>(B, W2, row_st, T);
    gather_range<<<N_NODES / 8, 256, 0, stream>>>(T, row_st, csr, b2, B);
    gemm128<<<(N_NODES + 63) / 64, 256, 0, stream>>>(B, W3, row_st, T);
    gather_range<<<N_NODES / 8, 256, 0, stream>>>(T, row_st, csr, b3, B);

    // 4. pool + head
    pool<<<(N_NODES / 8 + 7) / 8, 256, 0, stream>>>(B, batch, sums, counts);
    final_gemm<<<N_GRAPHS, 64, 0, stream>>>(sums, counts, Wout, bout, out);
}

// Round 7
// 401.026 us; speedup vs baseline: 21.6382x; 1.2164x over previous
//
#include <hip/hip_runtime.h>
#include <hip/hip_fp16.h>

#define N_NODES 100000
#define N_EDGES 1600000
#define N_GRAPHS 512
#define F_IN 20
#define HID 128
#define OUT_F 64

#define BUCKETS 256
#define SPAN 391        // ceil(N_NODES / BUCKETS)
#define BCAP 7000       // per-bucket capacity (mean 6250, ~9 sigma headroom)
#define EPB 2048        // edges per partition block

typedef _Float16 half8_t __attribute__((ext_vector_type(8)));
typedef float f32x4_t __attribute__((ext_vector_type(4)));

__device__ inline float4 h4_to_f4(uint2 u) {
    __half2 h0 = *(__half2*)&u.x;
    __half2 h1 = *(__half2*)&u.y;
    float2 f0 = __half22float2(h0);
    float2 f1 = __half22float2(h1);
    return make_float4(f0.x, f0.y, f1.x, f1.y);
}

// ---------------- zero sums/counts/cursors ----------------
__global__ void zero_all(float* sums, float* counts, int* cur256) {
    int i = blockIdx.x * 256 + threadIdx.x;
    sums[i] = 0.f;                            // exactly N_GRAPHS*HID
    if (i < N_GRAPHS) counts[i] = 0.f;
    if (i >= 512 && i < 512 + BUCKETS) cur256[i - 512] = 0;
}

// ---------------- partition edges into 256 dst-range buckets (packed) ----------------
__global__ __launch_bounds__(256) void partition(const int* __restrict__ src,
                                                 const int* __restrict__ dst,
                                                 int* __restrict__ bpairs,
                                                 int* cur256) {
    __shared__ int lcnt[BUCKETS];
    __shared__ int lbase[BUCKETS];
    int t = threadIdx.x;
    lcnt[t] = 0;
    __syncthreads();
    int base = blockIdx.x * EPB;
    int myb[8], myp[8];
#pragma unroll
    for (int i = 0; i < 8; ++i) {
        int e = base + i * 256 + t;
        int b = -1, p = 0;
        if (e < N_EDGES) {
            int s = src[e], d = dst[e];
            b = d / SPAN;
            p = (s << 9) | (d - b * SPAN);
            atomicAdd(&lcnt[b], 1);
        }
        myb[i] = b; myp[i] = p;
    }
    __syncthreads();
    lbase[t] = atomicAdd(&cur256[t], lcnt[t]);
    lcnt[t] = 0;
    __syncthreads();
#pragma unroll
    for (int i = 0; i < 8; ++i) {
        int b = myb[i];
        if (b >= 0) {
            int p = lbase[b] + atomicAdd(&lcnt[b], 1);
            if (p < BCAP) bpairs[(size_t)b * BCAP + p] = myp[i];
        }
    }
}

// ---------------- exclusive scan of bucket counts ----------------
__global__ void scan_bbase(const int* __restrict__ cur256, int* bbase, int* row_st) {
    __shared__ int sc[BUCKETS];
    int t = threadIdx.x;
    int v = cur256[t];
    sc[t] = v;
    __syncthreads();
    for (int o = 1; o < BUCKETS; o <<= 1) {
        int x = (t >= o) ? sc[t - o] : 0;
        __syncthreads();
        sc[t] += x;
        __syncthreads();
    }
    bbase[t] = sc[t] - v;
    if (t == 0) row_st[N_NODES] = N_EDGES;
}

// ---------------- per-bucket CSR build ----------------
__global__ __launch_bounds__(256) void csr_build(const int* __restrict__ bpairs,
                                                 const int* __restrict__ bcnt,
                                                 const int* __restrict__ bbase,
                                                 int* __restrict__ row_st,
                                                 int* __restrict__ csr) {
    __shared__ int ocnt[SPAN];
    __shared__ int sc[512];
    __shared__ int cur[SPAN];
    int b = blockIdx.x, t = threadIdx.x;
    int n0 = b * SPAN;
    int span = N_NODES - n0; if (span > SPAN) span = SPAN;
    for (int i = t; i < SPAN; i += 256) ocnt[i] = 0;
    __syncthreads();
    int n = bcnt[b];
    const int* p = bpairs + (size_t)b * BCAP;
    for (int i = t; i < n; i += 256) atomicAdd(&ocnt[p[i] & 511], 1);
    __syncthreads();
    sc[t]       = (t < span) ? ocnt[t] : 0;
    sc[t + 256] = (t + 256 < span) ? ocnt[t + 256] : 0;
    __syncthreads();
    for (int o = 1; o < 512; o <<= 1) {
        int a0 = (t >= o) ? sc[t - o] : 0;
        int a1 = sc[t + 256 - o];
        __syncthreads();
        sc[t] += a0;
        sc[t + 256] += a1;
        __syncthreads();
    }
    int base = bbase[b];
    for (int i = t; i < span; i += 256) {
        int start = sc[i] - ocnt[i];
        row_st[n0 + i] = base + start;
        cur[i] = start;
    }
    __syncthreads();
    for (int i = t; i < n; i += 256) {
        int e = p[i];
        int lp = atomicAdd(&cur[e & 511], 1);
        csr[base + lp] = e >> 9;
    }
}

// ---------------- layer 1: Xs = fp16(dinv * x), rows padded to 32 halves ----------------
__global__ void scale_x(const float* __restrict__ x, const int* __restrict__ row_st,
                        __half* __restrict__ Xs) {
    int i = blockIdx.x * 256 + threadIdx.x;   // over N_NODES*32
    int n = i >> 5, f = i & 31;
    if (n >= N_NODES) return;
    float v = (f < F_IN) ? x[n * F_IN + f] : 0.f;
    float di = rsqrtf((float)(row_st[n + 1] - row_st[n] + 1));
    Xs[i] = __float2half(di * v);
}

// ---------------- layer 1: Xagg[n] = dinv[n] * (Xs[n] + sum Xs[src]) ----------------
__global__ __launch_bounds__(256) void gather20(const __half* __restrict__ Xs,
                                                const int* __restrict__ row_st,
                                                const int* __restrict__ csr,
                                                float* __restrict__ Xagg) {
    int t = threadIdx.x;
    if (t >= 240) return;
    int g = t / F_IN, f = t % F_IN;
    int n = blockIdx.x * 12 + g;
    if (n >= N_NODES) return;
    int r0 = row_st[n], r1 = row_st[n + 1];
    float acc = __half2float(Xs[n * 32 + f]);   // self term
    int r = r0;
    for (; r + 3 < r1; r += 4) {
        int s0 = csr[r], s1 = csr[r + 1], s2 = csr[r + 2], s3 = csr[r + 3];
        float v0 = __half2float(Xs[s0 * 32 + f]);
        float v1 = __half2float(Xs[s1 * 32 + f]);
        float v2 = __half2float(Xs[s2 * 32 + f]);
        float v3 = __half2float(Xs[s3 * 32 + f]);
        acc += (v0 + v1) + (v2 + v3);
    }
    for (; r < r1; ++r) acc += __half2float(Xs[csr[r] * 32 + f]);
    float di = rsqrtf((float)(r1 - r0 + 1));
    Xagg[n * F_IN + f] = di * acc;
}

// ---------------- layer 1 GEMM: H = Xagg @ W1 + b1 (fp16 out) ----------------
__global__ __launch_bounds__(256) void gemm_l1(const float* __restrict__ A,
                                               const float* __restrict__ W,
                                               const float* __restrict__ bias,
                                               __half* __restrict__ C) {
    __shared__ float Alds[16 * F_IN];
    __shared__ float Wlds[F_IN * HID];
    const int t = threadIdx.x;
    const int node0 = blockIdx.x * 16;

    for (int idx = t; idx < 16 * F_IN; idx += 256)
        Alds[idx] = A[node0 * F_IN + idx];
    for (int idx = t; idx < F_IN * HID; idx += 256)
        Wlds[idx] = W[idx];
    __syncthreads();

    const int h4 = (t & 31) * 4;
    const int g  = t >> 5;
    float4 b4 = *(const float4*)&bias[h4];
    float4 acc0 = b4;
    float4 acc1 = b4;
#pragma unroll
    for (int kk = 0; kk < F_IN; ++kk) {
        float a0 = Alds[(g * 2) * F_IN + kk];
        float a1 = Alds[(g * 2 + 1) * F_IN + kk];
        float4 w = *(const float4*)&Wlds[kk * HID + h4];
        acc0.x = fmaf(a0, w.x, acc0.x);
        acc0.y = fmaf(a0, w.y, acc0.y);
        acc0.z = fmaf(a0, w.z, acc0.z);
        acc0.w = fmaf(a0, w.w, acc0.w);
        acc1.x = fmaf(a1, w.x, acc1.x);
        acc1.y = fmaf(a1, w.y, acc1.y);
        acc1.z = fmaf(a1, w.z, acc1.z);
        acc1.w = fmaf(a1, w.w, acc1.w);
    }
    {
        __half2 h0 = __floats2half2_rn(acc0.x, acc0.y);
        __half2 h1 = __floats2half2_rn(acc0.z, acc0.w);
        uint2 u; u.x = *(unsigned*)&h0; u.y = *(unsigned*)&h1;
        ((uint2*)C)[(node0 + g * 2) * 32 + (h4 >> 2)] = u;
    }
    {
        __half2 h0 = __floats2half2_rn(acc1.x, acc1.y);
        __half2 h1 = __floats2half2_rn(acc1.z, acc1.w);
        uint2 u; u.x = *(unsigned*)&h0; u.y = *(unsigned*)&h1;
        ((uint2*)C)[(node0 + g * 2 + 1) * 32 + (h4 >> 2)] = u;
    }
}

// ---------------- layers-2/3 GEMM via MFMA: T = dinv * (relu(H) @ W) ----------------
// W staged in LDS transposed (Wt[col][k]) split into fp16 hi + 2048*lo, k-groups
// XOR-swizzled by (col&15) so stride stays 128 (64 KB total) with balanced banks.
__global__ __launch_bounds__(256) void gemm_mfma(const __half* __restrict__ H,
                                                 const float* __restrict__ W,
                                                 const int* __restrict__ row_st,
                                                 __half* __restrict__ T) {
    __shared__ _Float16 Whi[128 * 128];
    __shared__ _Float16 Wlo[128 * 128];
    const int t = threadIdx.x;

    // stage: read W[k][c] coalesced, write transposed+swizzled
    for (int i = t; i < 128 * 128; i += 256) {
        int k = i >> 7, c = i & 127;
        float w = W[i];
        _Float16 hi = (_Float16)w;
        _Float16 lo = (_Float16)((w - (float)hi) * 2048.0f);
        int addr = c * 128 + (((k >> 3) ^ (c & 15)) << 3) + (k & 7);
        Whi[addr] = hi;
        Wlo[addr] = lo;
    }
    __syncthreads();

    const int wv = t >> 6;      // wave 0..3
    const int l  = t & 63;
    const int lr = l & 15;      // row (A) / col (B) within tile
    const int lq = l >> 4;      // quad -> k-group

    for (int rep = 0; rep < 4; ++rep) {
        int strip = (blockIdx.x * 4 + wv) * 4 + rep;
        if (strip >= N_NODES / 16) continue;
        int n0 = strip * 16;

        f32x4_t acc[8], acl[8];
#pragma unroll
        for (int ct = 0; ct < 8; ++ct) { acc[ct] = (f32x4_t){0,0,0,0}; acl[ct] = (f32x4_t){0,0,0,0}; }

#pragma unroll
        for (int kc = 0; kc < 4; ++kc) {
            // A-frag: relu(H[n0+lr][kc*32 + lq*8 .. +8])
            half8_t a = *(const half8_t*)(H + (size_t)(n0 + lr) * 128 + kc * 32 + lq * 8);
#pragma unroll
            for (int j = 0; j < 8; ++j) a[j] = a[j] > (_Float16)0 ? a[j] : (_Float16)0;
            int g = kc * 4 + lq;   // k-group index
#pragma unroll
            for (int ct = 0; ct < 8; ++ct) {
                int c = ct * 16 + lr;
                int addr = c * 128 + ((g ^ lr) << 3);
                half8_t bh = *(const half8_t*)&Whi[addr];
                half8_t bl = *(const half8_t*)&Wlo[addr];
                acc[ct] = __builtin_amdgcn_mfma_f32_16x16x32_f16(a, bh, acc[ct], 0, 0, 0);
                acl[ct] = __builtin_amdgcn_mfma_f32_16x16x32_f16(a, bl, acl[ct], 0, 0, 0);
            }
        }

        // epilogue: D[row][col], col=lr + 16*ct, row = n0 + lq*4 + r
        int r0 = n0 + lq * 4;
#pragma unroll
        for (int r = 0; r < 4; ++r) {
            int row = r0 + r;
            float d = rsqrtf((float)(row_st[row + 1] - row_st[row] + 1));
#pragma unroll
            for (int ct = 0; ct < 8; ++ct) {
                float v = (acc[ct][r] + acl[ct][r] * 4.8828125e-4f) * d;
                T[(size_t)row * 128 + ct * 16 + lr] = __float2half(v);
            }
        }
    }
}

// ---------------- gather (fp16 rows): H[n] = fp16(bias + dinv[n]*(T[n] + sum T[srcs])) ----------------
__global__ __launch_bounds__(256) void gather_range(const __half* __restrict__ A,
                                                    const int* __restrict__ row_st,
                                                    const int* __restrict__ csr,
                                                    const float* __restrict__ bias,
                                                    __half* __restrict__ B) {
    int t = threadIdx.x;
    int n = blockIdx.x * 8 + (t >> 5);
    int l = t & 31;
    int r0 = row_st[n], r1 = row_st[n + 1];
    float di = rsqrtf((float)(r1 - r0 + 1));
    const uint2* Af = (const uint2*)A;
    float4 acc = h4_to_f4(Af[n * 32 + l]);   // self term
    int r = r0;
    for (; r + 3 < r1; r += 4) {
        int s0 = csr[r];
        int s1 = csr[r + 1];
        int s2 = csr[r + 2];
        int s3 = csr[r + 3];
        float4 v0 = h4_to_f4(Af[s0 * 32 + l]);
        float4 v1 = h4_to_f4(Af[s1 * 32 + l]);
        float4 v2 = h4_to_f4(Af[s2 * 32 + l]);
        float4 v3 = h4_to_f4(Af[s3 * 32 + l]);
        acc.x += (v0.x + v1.x) + (v2.x + v3.x);
        acc.y += (v0.y + v1.y) + (v2.y + v3.y);
        acc.z += (v0.z + v1.z) + (v2.z + v3.z);
        acc.w += (v0.w + v1.w) + (v2.w + v3.w);
    }
    for (; r < r1; ++r) {
        float4 v = h4_to_f4(Af[csr[r] * 32 + l]);
        acc.x += v.x; acc.y += v.y; acc.z += v.z; acc.w += v.w;
    }
    float4 b4 = ((const float4*)bias)[l];
    __half2 h0 = __floats2half2_rn(fmaf(di, acc.x, b4.x), fmaf(di, acc.y, b4.y));
    __half2 h1 = __floats2half2_rn(fmaf(di, acc.z, b4.z), fmaf(di, acc.w, b4.w));
    uint2 u; u.x = *(unsigned*)&h0; u.y = *(unsigned*)&h1;
    ((uint2*)B)[n * 32 + l] = u;
}

// ---------------- pooling (fp16 input, fused counting; batch sorted) ----------------
__global__ __launch_bounds__(256) void pool(const __half* __restrict__ B,
                                            const int* __restrict__ batch,
                                            float* sums, float* counts) {
    int t = threadIdx.x;
    int grp = blockIdx.x * 8 + (t >> 5);
    int l = t & 31;
    int h4 = l * 4;
    int n0 = grp * 8;
    if (n0 >= N_NODES) return;
    const uint2* Bf = (const uint2*)B;
    int cur = batch[n0];
    int runlen = 0;
    float4 acc = make_float4(0.f, 0.f, 0.f, 0.f);
    for (int k = 0; k < 8; ++k) {
        int n = n0 + k;
        if (n >= N_NODES) break;
        int g = batch[n];
        if (g != cur) {
            float* sp = &sums[cur * HID + h4];
            atomicAdd(sp + 0, acc.x); atomicAdd(sp + 1, acc.y);
            atomicAdd(sp + 2, acc.z); atomicAdd(sp + 3, acc.w);
            if (l == 0) atomicAdd(&counts[cur], (float)runlen);
            acc = make_float4(0.f, 0.f, 0.f, 0.f);
            runlen = 0;
            cur = g;
        }
        float4 v = h4_to_f4(Bf[n * 32 + l]);
        acc.x += fmaxf(v.x, 0.f);
        acc.y += fmaxf(v.y, 0.f);
        acc.z += fmaxf(v.z, 0.f);
        acc.w += fmaxf(v.w, 0.f);
        ++runlen;
    }
    float* sp = &sums[cur * HID + h4];
    atomicAdd(sp + 0, acc.x); atomicAdd(sp + 1, acc.y);
    atomicAdd(sp + 2, acc.z); atomicAdd(sp + 3, acc.w);
    if (l == 0) atomicAdd(&counts[cur], (float)runlen);
}

__global__ void final_gemm(const float* __restrict__ sums, const float* __restrict__ counts,
                           const float* __restrict__ Wout, const float* __restrict__ bout,
                           float* __restrict__ out) {
    int g = blockIdx.x;
    int o = threadIdx.x;   // 64
    __shared__ float p[HID];
    for (int k = o; k < HID; k += 64) p[k] = sums[g * HID + k];
    __syncthreads();
    float inv = 1.0f / fmaxf(counts[g], 1.0f);
    float acc = 0.f;
#pragma unroll 8
    for (int k = 0; k < HID; ++k)
        acc = fmaf(p[k], Wout[k * OUT_F + o], acc);
    out[g * OUT_F + o] = fmaf(inv, acc, bout[o]);
}

extern "C" void kernel_launch(void* const* d_in, const int* in_sizes, int n_in,
                              void* d_out, int out_size, void* d_ws, size_t ws_size,
                              hipStream_t stream) {
    const float* x     = (const float*)d_in[0];
    const int*   ei    = (const int*)d_in[1];
    const int*   batch = (const int*)d_in[2];
    const float* W1    = (const float*)d_in[3];
    const float* b1    = (const float*)d_in[4];
    const float* W2    = (const float*)d_in[5];
    const float* b2    = (const float*)d_in[6];
    const float* W3    = (const float*)d_in[7];
    const float* b3    = (const float*)d_in[8];
    const float* Wout  = (const float*)d_in[9];
    const float* bout  = (const float*)d_in[10];
    float* out = (float*)d_out;

    const int* src = ei;
    const int* dst = ei + N_EDGES;

    // workspace (same proven footprint as rounds 4-6)
    float* A      = (float*)d_ws;                        // 12.8M floats
    float* Breg   = A + (size_t)N_NODES * HID;           // 12.8M floats
    int*   row_st = (int*)(Breg + (size_t)N_NODES * HID);// 100001 ints
    float* sums   = (float*)(row_st + N_NODES + 1);      // 65536
    float* counts = sums + N_GRAPHS * HID;               // 512
    int*   csr    = (int*)(counts + N_GRAPHS);           // 1.6M ints
    int*   cur256 = csr + N_EDGES;                       // 256
    int*   bbase  = cur256 + BUCKETS;                    // 256

    int*    bpairs = (int*)A;             // 7.2 MB overlay, dead after csr_build
    __half* Xs     = (__half*)A;          // N_NODES*32 halves (6.4 MB)
    float*  Xagg   = A + 1600000;         // N_NODES*F_IN floats, after Xs
    __half* T      = (__half*)A;          // fp16 message table (25.6 MB), overlays A
    __half* H      = (__half*)Breg;       // fp16 activation table (25.6 MB)

    // 1. zero + CSR build
    zero_all<<<N_GRAPHS * HID / 256, 256, 0, stream>>>(sums, counts, cur256);
    partition<<<(N_EDGES + EPB - 1) / EPB, 256, 0, stream>>>(src, dst, bpairs, cur256);
    scan_bbase<<<1, BUCKETS, 0, stream>>>(cur256, bbase, row_st);
    csr_build<<<BUCKETS, 256, 0, stream>>>(bpairs, cur256, bbase, row_st, csr);

    // 2. layer 1: aggregate in F_IN=20 (fp16 rows, 64B-padded), then transform
    scale_x<<<N_NODES * 32 / 256, 256, 0, stream>>>(x, row_st, Xs);
    gather20<<<(N_NODES + 11) / 12, 256, 0, stream>>>(Xs, row_st, csr, Xagg);
    gemm_l1<<<N_NODES / 16, 256, 0, stream>>>(Xagg, W1, b1, H);

    // 3. layers 2/3: MFMA transform (ReLU fused) then aggregate
    gemm_mfma<<<391, 256, 0, stream>>>(H, W2, row_st, T);
    gather_range<<<N_NODES / 8, 256, 0, stream>>>(T, row_st, csr, b2, H);
    gemm_mfma<<<391, 256, 0, stream>>>(H, W3, row_st, T);
    gather_range<<<N_NODES / 8, 256, 0, stream>>>(T, row_st, csr, b3, H);

    // 4. pool + head
    pool<<<(N_NODES / 8 + 7) / 8, 256, 0, stream>>>(H, batch, sums, counts);
    final_gemm<<<N_GRAPHS, 64, 0, stream>>>(sums, counts, Wout, bout, out);
}